// Round 8
// baseline (744.792 us; speedup 1.0000x reference)
//
#include <hip/hip_runtime.h>

typedef unsigned short u16;
typedef float f32x4 __attribute__((ext_vector_type(4)));
typedef short bf16x8 __attribute__((ext_vector_type(8)));
typedef unsigned short u16x8 __attribute__((ext_vector_type(8)));

#define ND 768
#define KD 768

__device__ __forceinline__ float bf2f(u16 u) {
    union { unsigned i; float f; } v; v.i = ((unsigned)u) << 16; return v.f;
}
__device__ __forceinline__ u16 f2bf(float f) {
    union { float f; unsigned u; } x; x.f = f;
    unsigned r = x.u + 0x7fffu + ((x.u >> 16) & 1u);
    return (u16)(r >> 16);
}
__device__ __forceinline__ void async16(const void* g, void* l) {
    __builtin_amdgcn_global_load_lds((const __attribute__((address_space(1))) void*)g,
                                     (__attribute__((address_space(3))) void*)l, 16, 0, 0);
}

// ---- transpose+convert weights via LDS tiles: Wt[m][n][k] = bf16(W_m[k][n]) ----
__global__ __launch_bounds__(256) void conv_w(const float* __restrict__ W_emb,
                                              const float* __restrict__ gat_W,
                                              const float* __restrict__ W_out,
                                              u16* __restrict__ Wt)
{
    __shared__ float lds[64][65];
    const int m  = blockIdx.x / 144;
    const int r  = blockIdx.x % 144;
    const int tr = r / 12;
    const int tc = r % 12;
    const float* src = (m == 0) ? W_emb : (m <= 3) ? (gat_W + (size_t)(m - 1) * 589824) : W_out;
    const int c  = threadIdx.x & 63;
    const int w4 = threadIdx.x >> 6;
    #pragma unroll
    for (int i = 0; i < 16; ++i) {
        int kk = i * 4 + w4;
        lds[kk][c] = src[(size_t)(tr * 64 + kk) * 768 + tc * 64 + c];
    }
    __syncthreads();
    u16* dst = Wt + (size_t)m * 589824;
    #pragma unroll
    for (int i = 0; i < 16; ++i) {
        int nn = i * 4 + w4;
        dst[(size_t)(tc * 64 + nn) * 768 + tr * 64 + c] = f2bf(lds[c][nn]);
    }
}

// ---- fp32 -> bf16 bulk convert ----
__global__ __launch_bounds__(256) void conv_x(const float4* __restrict__ in,
                                              u16* __restrict__ outp, int n4)
{
    for (int i = blockIdx.x * 256 + threadIdx.x; i < n4; i += gridDim.x * 256) {
        float4 v = in[i];
        union { u16 s[4]; uint2 u; } o;
        o.s[0] = f2bf(v.x); o.s[1] = f2bf(v.y); o.s[2] = f2bf(v.z); o.s[3] = f2bf(v.w);
        ((uint2*)outp)[i] = o.u;
    }
}

// ---- 8-phase-style bf16 GEMM: C[m][n] = sum_k A[m][k]*Bt[n][k] (+bias) ----
// 256x256 tile, 8 waves (2Mx4N), wave-tile 128x64, BK=32 slots in a 4-deep
// circular LDS queue (4x32KB). Per slot: 2 phases {ds_reads | 2 gloads |
// barrier | setprio 16 MFMA | barrier}; counted vmcnt(8) once per slot
// validates buf t+1 (loads land 3 slots early). T2 involution swizzle
// (verified R5/R6): phys 16B chunk = logical ^ ((row>>1)&3).
template<bool F32OUT>
__global__ __launch_bounds__(512, 2) void gemm8p(const u16* __restrict__ A,
                                                 const u16* __restrict__ Bt,
                                                 const float* __restrict__ bias,
                                                 void* __restrict__ Cout)
{
    __shared__ u16 lds[4 * 16384];   // 4 slots x (A 8192 u16 | B 8192 u16)
    const int tid  = threadIdx.x;
    const int lane = tid & 63;
    const int wid  = tid >> 6;
    const int wr   = wid >> 2;       // 0..1  -> rows wr*128
    const int wc   = wid & 3;        // 0..3  -> cols wc*64
    // XCD-chunked bijective swizzle: 672 = 8 * 84; M-major inside a chunk.
    const int wg = blockIdx.x;
    const int id = (wg & 7) * 84 + (wg >> 3);
    const int tm = (id / 3) * 256;
    const int tn = (id % 3) * 256;

    const int lr  = lane & 15;
    const int lsl = lane >> 4;
    const int lk  = ((lsl ^ ((lr >> 1) & 3)) << 3);
    const int offA0 = (wr * 128 + lr) * 32 + lk;   // + mf*512
    const int offB0 = (wc * 64 + lr) * 32 + lk;    // + nf*512

    // staging: thread covers rows (tid>>2) and +128, pre-swizzled chunk kc0
    const int wvb8 = (tid & ~63) * 8;
    const int kc0  = (((tid & 3) ^ ((tid >> 3) & 3)) << 3);
    const int row0 = tid >> 2;
    const u16* aS0 = A  + (size_t)(tm + row0) * KD + kc0;
    const u16* aS1 = aS0 + (size_t)128 * KD;
    const u16* bS0 = Bt + (size_t)(tn + row0) * KD + kc0;
    const u16* bS1 = bS0 + (size_t)128 * KD;

    f32x4 acc[8][4] = {};

#define STAGE_A(s_, t_) { u16* d = &lds[(s_) * 16384 + wvb8]; const int k0 = (t_) * 32; \
        async16(aS0 + k0, d); async16(aS1 + k0, d + 4096); }
#define STAGE_B(s_, t_) { u16* d = &lds[(s_) * 16384 + 8192 + wvb8]; const int k0 = (t_) * 32; \
        async16(bS0 + k0, d); async16(bS1 + k0, d + 4096); }

    // prologue: stage slots 0..2 (12 gloads), validate slot 0
    STAGE_A(0, 0) STAGE_B(0, 0)
    STAGE_A(1, 1) STAGE_B(1, 1)
    STAGE_A(2, 2) STAGE_B(2, 2)
    asm volatile("s_waitcnt vmcnt(8)" ::: "memory");
    __builtin_amdgcn_s_barrier();
    asm volatile("" ::: "memory");

    #pragma unroll 1
    for (int t = 0; t < 24; ++t) {
        const u16* As = &lds[(t & 3) * 16384];
        const u16* Bs = As + 8192;
        // ---------- phase A: af[0..7], bf[0..1]; stage A of slot t+3 ----------
        bf16x8 af[8], bf[4];
        #pragma unroll
        for (int mf = 0; mf < 8; ++mf)
            af[mf] = *(const bf16x8*)&As[offA0 + mf * 512];
        bf[0] = *(const bf16x8*)&Bs[offB0];
        bf[1] = *(const bf16x8*)&Bs[offB0 + 512];
        if (t + 3 < 24) STAGE_A((t + 3) & 3, t + 3)
        __builtin_amdgcn_s_barrier();
        asm volatile("" ::: "memory");
        __builtin_amdgcn_s_setprio(1);
        #pragma unroll
        for (int mf = 0; mf < 8; ++mf) {
            acc[mf][0] = __builtin_amdgcn_mfma_f32_16x16x32_bf16(af[mf], bf[0], acc[mf][0], 0, 0, 0);
            acc[mf][1] = __builtin_amdgcn_mfma_f32_16x16x32_bf16(af[mf], bf[1], acc[mf][1], 0, 0, 0);
        }
        __builtin_amdgcn_s_setprio(0);
        __builtin_amdgcn_s_barrier();
        asm volatile("" ::: "memory");
        // ---------- phase B: bf[2..3]; stage B of slot t+3; validate t+1 ----------
        bf[2] = *(const bf16x8*)&Bs[offB0 + 1024];
        bf[3] = *(const bf16x8*)&Bs[offB0 + 1536];
        if (t + 3 < 24) STAGE_B((t + 3) & 3, t + 3)
        if (t < 23) {
            if (t <= 20)      asm volatile("s_waitcnt vmcnt(8)" ::: "memory");
            else if (t == 21) asm volatile("s_waitcnt vmcnt(4)" ::: "memory");
            else              asm volatile("s_waitcnt vmcnt(0)" ::: "memory");
        }
        __builtin_amdgcn_s_barrier();
        asm volatile("" ::: "memory");
        __builtin_amdgcn_s_setprio(1);
        #pragma unroll
        for (int mf = 0; mf < 8; ++mf) {
            acc[mf][2] = __builtin_amdgcn_mfma_f32_16x16x32_bf16(af[mf], bf[2], acc[mf][2], 0, 0, 0);
            acc[mf][3] = __builtin_amdgcn_mfma_f32_16x16x32_bf16(af[mf], bf[3], acc[mf][3], 0, 0, 0);
        }
        __builtin_amdgcn_s_setprio(0);
        __builtin_amdgcn_s_barrier();
        asm volatile("" ::: "memory");
    }
#undef STAGE_A
#undef STAGE_B

    // epilogue: C/D layout col=lane&15, row=(lane>>4)*4+reg
    const int lr4 = lsl << 2;
    #pragma unroll
    for (int nf = 0; nf < 4; ++nf) {
        int col = tn + wc * 64 + nf * 16 + lr;
        float bv = bias ? bias[col] : 0.0f;
        #pragma unroll
        for (int mf = 0; mf < 8; ++mf) {
            int rowb = tm + wr * 128 + mf * 16 + lr4;
            #pragma unroll
            for (int r = 0; r < 4; ++r) {
                float v = acc[mf][nf][r] + bv;
                if (F32OUT)
                    ((float*)Cout)[(size_t)(rowb + r) * ND + col] = v;
                else
                    ((u16*)Cout)[(size_t)(rowb + r) * ND + col] = f2bf(v);
            }
        }
    }
}

// ---- fused GAT attention per batch: ei/ej from staged Wh, softmax, mix, ELU ----
// LDS-staged (safe when Xout aliases Wh).
template<bool ELU>
__global__ __launch_bounds__(256) void gat_mix(const u16* __restrict__ Wh,
                                               const float* __restrict__ adj,
                                               const float* __restrict__ avec,
                                               float* __restrict__ attn_out,
                                               u16* __restrict__ Xout)
{
    __shared__ u16 wh[14 * 768];
    __shared__ float s_ei[14], s_ej[14];
    __shared__ float s_attn[196];
    const int b = blockIdx.x;
    const int tid = threadIdx.x;
    const u16* whb = Wh + (size_t)b * 10752;

    for (int c = tid; c < 1344; c += 256)
        ((uint4*)wh)[c] = ((const uint4*)whb)[c];
    __syncthreads();

    // ei/ej: 14 rows x 16 lanes, each lane sums 6 chunks of 8, 4-step shuffle
    if (tid < 224) {
        const int i = tid >> 4, l = tid & 15;
        float ai = 0.f, aj = 0.f;
        #pragma unroll
        for (int c = 0; c < 6; ++c) {
            int d = c * 128 + l * 8;
            u16x8 v  = *(const u16x8*)&wh[i * 768 + d];
            float4 x0 = *(const float4*)&avec[d];
            float4 x1 = *(const float4*)&avec[d + 4];
            float4 y0 = *(const float4*)&avec[768 + d];
            float4 y1 = *(const float4*)&avec[768 + d + 4];
            float w0 = bf2f(v[0]), w1 = bf2f(v[1]), w2 = bf2f(v[2]), w3 = bf2f(v[3]);
            float w4 = bf2f(v[4]), w5 = bf2f(v[5]), w6 = bf2f(v[6]), w7 = bf2f(v[7]);
            ai += w0*x0.x + w1*x0.y + w2*x0.z + w3*x0.w + w4*x1.x + w5*x1.y + w6*x1.z + w7*x1.w;
            aj += w0*y0.x + w1*y0.y + w2*y0.z + w3*y0.w + w4*y1.x + w5*y1.y + w6*y1.z + w7*y1.w;
        }
        #pragma unroll
        for (int off = 8; off; off >>= 1) {
            ai += __shfl_xor(ai, off);
            aj += __shfl_xor(aj, off);
        }
        if (l == 0) { s_ei[i] = ai; s_ej[i] = aj; }
    }
    __syncthreads();

    // masked softmax over j per row i (N=14, fp32)
    if (tid < 14) {
        const int i = tid;
        float e[14];
        float mx = -3.0e38f;
        #pragma unroll
        for (int j = 0; j < 14; ++j) {
            float ev = (adj[(size_t)b * 196 + i * 14 + j] > 0.f) ? (s_ei[i] + s_ej[j]) : -1.0e30f;
            e[j] = ev; mx = fmaxf(mx, ev);
        }
        float sum = 0.f;
        #pragma unroll
        for (int j = 0; j < 14; ++j) { float pp = __expf(e[j] - mx); e[j] = pp; sum += pp; }
        float inv = 1.0f / sum;
        #pragma unroll
        for (int j = 0; j < 14; ++j) s_attn[i * 14 + j] = e[j] * inv;
    }
    __syncthreads();

    if (tid < 196) attn_out[(size_t)b * 196 + tid] = s_attn[tid];

    // mix: h[i,d] = sum_j attn[i,j]*Wh[j,d]; opt ELU; write bf16 (16 elems/item)
    for (int pp = tid; pp < 14 * 48; pp += 256) {
        const int i  = pp / 48;
        const int d0 = (pp % 48) * 16;
        float acc[16] = {};
        #pragma unroll
        for (int j = 0; j < 14; ++j) {
            float aw = s_attn[i * 14 + j];
            u16x8 wv0 = *(const u16x8*)&wh[j * 768 + d0];
            u16x8 wv1 = *(const u16x8*)&wh[j * 768 + d0 + 8];
            #pragma unroll
            for (int qq = 0; qq < 8; ++qq) {
                acc[qq]     += aw * bf2f(wv0[qq]);
                acc[8 + qq] += aw * bf2f(wv1[qq]);
            }
        }
        union { u16 s[16]; uint4 u[2]; } o;
        #pragma unroll
        for (int qq = 0; qq < 16; ++qq) {
            float v = acc[qq];
            if (ELU && v < 0.f) v = __expf(v) - 1.0f;
            o.s[qq] = f2bf(v);
        }
        *(uint4*)&Xout[(size_t)b * 10752 + i * 768 + d0]     = o.u[0];
        *(uint4*)&Xout[(size_t)b * 10752 + i * 768 + d0 + 8] = o.u[1];
    }
}

extern "C" void kernel_launch(void* const* d_in, const int* in_sizes, int n_in,
                              void* d_out, int out_size, void* d_ws, size_t ws_size,
                              hipStream_t stream)
{
    const float* features = (const float*)d_in[0];
    const float* adj      = (const float*)d_in[1];
    const float* W_emb    = (const float*)d_in[2];
    const float* b_emb    = (const float*)d_in[3];
    const float* gat_W    = (const float*)d_in[4];
    const float* gat_a    = (const float*)d_in[5];
    const float* W_out    = (const float*)d_in[6];
    const float* b_out    = (const float*)d_in[7];
    float* out = (float*)d_out;

    // ws: Wh (bf16 57344x768) | Wt (5 transposed bf16 mats)
    u16* Wh = (u16*)d_ws;
    u16* Wt = Wh + 44040192;
    // out-region as two bf16 x ping-pong halves until the final GEMM
    u16* H0 = (u16*)d_out;
    u16* H1 = H0 + 44040192;
    float* attn0 = out + 44040192;
    float* attn1 = attn0 + 802816;
    float* attn2 = attn1 + 802816;

    conv_w<<<dim3(720), 256, 0, stream>>>(W_emb, gat_W, W_out, Wt);
    conv_x<<<dim3(4096), 256, 0, stream>>>((const float4*)features, H0, 11010048);

    dim3 gg(672);
    // x0 = features @ W_emb + b_emb
    gemm8p<false><<<gg, 512, 0, stream>>>(H0, Wt, b_emb, H1);
    // layer 0
    gemm8p<false><<<gg, 512, 0, stream>>>(H1, Wt + 589824, nullptr, Wh);
    gat_mix<true><<<dim3(4096), 256, 0, stream>>>(Wh, adj, gat_a, attn0, H0);
    // layer 1
    gemm8p<false><<<gg, 512, 0, stream>>>(H0, Wt + 2 * 589824, nullptr, Wh);
    gat_mix<true><<<dim3(4096), 256, 0, stream>>>(Wh, adj, gat_a + 1536, attn1, H1);
    // layer 2 (no ELU; x3 in-place over Wh -> staged kernel is safe)
    gemm8p<false><<<gg, 512, 0, stream>>>(H1, Wt + 3 * 589824, nullptr, Wh);
    gat_mix<false><<<dim3(4096), 256, 0, stream>>>(Wh, adj, gat_a + 3072, attn2, Wh);
    // out = x3 @ W_out + b_out (fp32)
    gemm8p<true><<<gg, 512, 0, stream>>>(Wh, Wt + 4 * 589824, b_out, (void*)out);
}

// Round 9
// 707.719 us; speedup vs baseline: 1.0524x; 1.0524x over previous
//
#include <hip/hip_runtime.h>

typedef unsigned short u16;
typedef float f32x4 __attribute__((ext_vector_type(4)));
typedef float f32x16 __attribute__((ext_vector_type(16)));
typedef short bf16x8 __attribute__((ext_vector_type(8)));
typedef unsigned short u16x8 __attribute__((ext_vector_type(8)));

#define ND 768
#define KD 768

__device__ __forceinline__ float bf2f(u16 u) {
    union { unsigned i; float f; } v; v.i = ((unsigned)u) << 16; return v.f;
}
__device__ __forceinline__ u16 f2bf(float f) {
    union { float f; unsigned u; } x; x.f = f;
    unsigned r = x.u + 0x7fffu + ((x.u >> 16) & 1u);
    return (u16)(r >> 16);
}
__device__ __forceinline__ void async16(const void* g, void* l) {
    __builtin_amdgcn_global_load_lds((const __attribute__((address_space(1))) void*)g,
                                     (__attribute__((address_space(3))) void*)l, 16, 0, 0);
}

// ---- transpose+convert weights via LDS tiles: Wt[m][n][k] = bf16(W_m[k][n]) ----
__global__ __launch_bounds__(256) void conv_w(const float* __restrict__ W_emb,
                                              const float* __restrict__ gat_W,
                                              const float* __restrict__ W_out,
                                              u16* __restrict__ Wt)
{
    __shared__ float lds[64][65];
    const int m  = blockIdx.x / 144;
    const int r  = blockIdx.x % 144;
    const int tr = r / 12;
    const int tc = r % 12;
    const float* src = (m == 0) ? W_emb : (m <= 3) ? (gat_W + (size_t)(m - 1) * 589824) : W_out;
    const int c  = threadIdx.x & 63;
    const int w4 = threadIdx.x >> 6;
    #pragma unroll
    for (int i = 0; i < 16; ++i) {
        int kk = i * 4 + w4;
        lds[kk][c] = src[(size_t)(tr * 64 + kk) * 768 + tc * 64 + c];
    }
    __syncthreads();
    u16* dst = Wt + (size_t)m * 589824;
    #pragma unroll
    for (int i = 0; i < 16; ++i) {
        int nn = i * 4 + w4;
        dst[(size_t)(tc * 64 + nn) * 768 + tr * 64 + c] = f2bf(lds[c][nn]);
    }
}

// ---- fp32 -> bf16 bulk convert ----
__global__ __launch_bounds__(256) void conv_x(const float4* __restrict__ in,
                                              u16* __restrict__ outp, int n4)
{
    for (int i = blockIdx.x * 256 + threadIdx.x; i < n4; i += gridDim.x * 256) {
        float4 v = in[i];
        union { u16 s[4]; uint2 u; } o;
        o.s[0] = f2bf(v.x); o.s[1] = f2bf(v.y); o.s[2] = f2bf(v.z); o.s[3] = f2bf(v.w);
        ((uint2*)outp)[i] = o.u;
    }
}

// ---- bf16 GEMM, 2-phase double-buffered prefetch + 32x32x16 MFMA ----
// C[m][n] = sum_k A[m][k]*Bt[n][k] (+bias). 128^2 tile, BK=32, 4 waves,
// wave-tile 64x64 as 2x2 frags of 32x32. Staging/swizzle byte-identical to
// R7 (verified): phys 16B chunk = logical ^ ((row>>1)&3); counted vmcnt(4).
template<bool F32OUT>
__global__ __launch_bounds__(256) void gemm_bt(const u16* __restrict__ A,
                                               const u16* __restrict__ Bt,
                                               const float* __restrict__ bias,
                                               void* __restrict__ Cout)
{
    __shared__ u16 lds2[2][2][4096];   // [buf][A=0/B=1][128 rows x 32 bf16]
    const int tid  = threadIdx.x;
    const int lane = tid & 63;
    const int wvb  = tid & ~63;              // wave*64
    const int wm   = ((tid >> 7) & 1) * 64;  // wave row block
    const int wn   = ((tid >> 6) & 1) * 64;  // wave col block
    // XCD-chunked bijective swizzle: 2688 = 8 * 336
    const int wg = blockIdx.x;
    const int id = (wg & 7) * 336 + (wg >> 3);
    const int tn = (id % 6) * 128;
    const int tm = (id / 6) * 128;

    f32x16 acc[2][2] = {};

    // 32x32 fragment read geometry: lane&31 = row-in-32block, lane>>5 = k-half
    const int r31 = lane & 31;
    const int l5  = lane >> 5;
    const int key = (r31 >> 1) & 3;          // swizzle key = (row>>1)&3

    // staging: thread covers rows row0 and row0+64, pre-swizzled k-chunk kc0
    const int row0 = tid >> 2;
    const int kc0  = (((tid & 3) ^ ((tid >> 3) & 3)) << 3);
    const u16* aSrc = A  + (size_t)(tm + row0) * KD + kc0;
    const u16* bSrc = Bt + (size_t)(tn + row0) * KD + kc0;

    #define STAGE(b, ks_) { const int k0 = (ks_) * 32;                      \
        async16(aSrc + k0,                  &lds2[b][0][wvb * 8]);          \
        async16(aSrc + (size_t)64 * KD + k0, &lds2[b][0][(256 + wvb) * 8]); \
        async16(bSrc + k0,                  &lds2[b][1][wvb * 8]);          \
        async16(bSrc + (size_t)64 * KD + k0, &lds2[b][1][(256 + wvb) * 8]); }

    STAGE(0, 0);

    #pragma unroll 2
    for (int ks = 0; ks < KD / 32; ++ks) {
        const int cur = ks & 1;
        if (ks + 1 < KD / 32) {
            STAGE(cur ^ 1, ks + 1);                         // prefetch next
            asm volatile("s_waitcnt vmcnt(4)" ::: "memory"); // oldest 4 = buf cur
        } else {
            asm volatile("s_waitcnt vmcnt(0)" ::: "memory");
        }
        __builtin_amdgcn_s_barrier();
        asm volatile("" ::: "memory");

        const u16* As = lds2[cur][0];
        const u16* Bs = lds2[cur][1];
        bf16x8 af[2][2], bf[2][2];
        #pragma unroll
        for (int fr = 0; fr < 2; ++fr)
            #pragma unroll
            for (int ka = 0; ka < 2; ++ka) {
                int chA = ((ka * 2 + l5) ^ key) << 3;
                af[fr][ka] = *(const bf16x8*)&As[(wm + fr * 32 + r31) * 32 + chA];
                bf[fr][ka] = *(const bf16x8*)&Bs[(wn + fr * 32 + r31) * 32 + chA];
            }
        #pragma unroll
        for (int fr = 0; fr < 2; ++fr)
            #pragma unroll
            for (int fc = 0; fc < 2; ++fc)
                #pragma unroll
                for (int ka = 0; ka < 2; ++ka)
                    acc[fr][fc] = __builtin_amdgcn_mfma_f32_32x32x16_bf16(
                        af[fr][ka], bf[fc][ka], acc[fr][fc], 0, 0, 0);

        if (ks + 1 < KD / 32) {        // protect buffers from next STAGE
            asm volatile("" ::: "memory");
            __builtin_amdgcn_s_barrier();
        }
    }
    #undef STAGE

    // epilogue: 32x32 C/D layout col=lane&31, row=(reg&3)+8*(reg>>2)+4*(lane>>5)
    #pragma unroll
    for (int fc = 0; fc < 2; ++fc) {
        int col = tn + wn + fc * 32 + r31;
        float bv = bias ? bias[col] : 0.0f;
        #pragma unroll
        for (int fr = 0; fr < 2; ++fr) {
            int rowb = tm + wm + fr * 32 + 4 * l5;
            #pragma unroll
            for (int reg = 0; reg < 16; ++reg) {
                int row = rowb + (reg & 3) + 8 * (reg >> 2);
                float v = acc[fr][fc][reg] + bv;
                if (F32OUT)
                    ((float*)Cout)[(size_t)row * ND + col] = v;
                else
                    ((u16*)Cout)[(size_t)row * ND + col] = f2bf(v);
            }
        }
    }
}

// ---- fused GAT attention per batch: ei/ej from staged Wh, softmax, mix, ELU ----
// LDS-staged (safe when Xout aliases Wh).
template<bool ELU>
__global__ __launch_bounds__(256) void gat_mix(const u16* __restrict__ Wh,
                                               const float* __restrict__ adj,
                                               const float* __restrict__ avec,
                                               float* __restrict__ attn_out,
                                               u16* __restrict__ Xout)
{
    __shared__ u16 wh[14 * 768];
    __shared__ float s_ei[14], s_ej[14];
    __shared__ float s_attn[196];
    const int b = blockIdx.x;
    const int tid = threadIdx.x;
    const u16* whb = Wh + (size_t)b * 10752;

    for (int c = tid; c < 1344; c += 256)
        ((uint4*)wh)[c] = ((const uint4*)whb)[c];
    __syncthreads();

    // ei/ej: 14 rows x 16 lanes, each lane sums 6 chunks of 8, 4-step shuffle
    if (tid < 224) {
        const int i = tid >> 4, l = tid & 15;
        float ai = 0.f, aj = 0.f;
        #pragma unroll
        for (int c = 0; c < 6; ++c) {
            int d = c * 128 + l * 8;
            u16x8 v  = *(const u16x8*)&wh[i * 768 + d];
            float4 x0 = *(const float4*)&avec[d];
            float4 x1 = *(const float4*)&avec[d + 4];
            float4 y0 = *(const float4*)&avec[768 + d];
            float4 y1 = *(const float4*)&avec[768 + d + 4];
            float w0 = bf2f(v[0]), w1 = bf2f(v[1]), w2 = bf2f(v[2]), w3 = bf2f(v[3]);
            float w4 = bf2f(v[4]), w5 = bf2f(v[5]), w6 = bf2f(v[6]), w7 = bf2f(v[7]);
            ai += w0*x0.x + w1*x0.y + w2*x0.z + w3*x0.w + w4*x1.x + w5*x1.y + w6*x1.z + w7*x1.w;
            aj += w0*y0.x + w1*y0.y + w2*y0.z + w3*y0.w + w4*y1.x + w5*y1.y + w6*y1.z + w7*y1.w;
        }
        #pragma unroll
        for (int off = 8; off; off >>= 1) {
            ai += __shfl_xor(ai, off);
            aj += __shfl_xor(aj, off);
        }
        if (l == 0) { s_ei[i] = ai; s_ej[i] = aj; }
    }
    __syncthreads();

    // masked softmax over j per row i (N=14, fp32)
    if (tid < 14) {
        const int i = tid;
        float e[14];
        float mx = -3.0e38f;
        #pragma unroll
        for (int j = 0; j < 14; ++j) {
            float ev = (adj[(size_t)b * 196 + i * 14 + j] > 0.f) ? (s_ei[i] + s_ej[j]) : -1.0e30f;
            e[j] = ev; mx = fmaxf(mx, ev);
        }
        float sum = 0.f;
        #pragma unroll
        for (int j = 0; j < 14; ++j) { float pp = __expf(e[j] - mx); e[j] = pp; sum += pp; }
        float inv = 1.0f / sum;
        #pragma unroll
        for (int j = 0; j < 14; ++j) s_attn[i * 14 + j] = e[j] * inv;
    }
    __syncthreads();

    if (tid < 196) attn_out[(size_t)b * 196 + tid] = s_attn[tid];

    // mix: h[i,d] = sum_j attn[i,j]*Wh[j,d]; opt ELU; write bf16 (16 elems/item)
    for (int pp = tid; pp < 14 * 48; pp += 256) {
        const int i  = pp / 48;
        const int d0 = (pp % 48) * 16;
        float acc[16] = {};
        #pragma unroll
        for (int j = 0; j < 14; ++j) {
            float aw = s_attn[i * 14 + j];
            u16x8 wv0 = *(const u16x8*)&wh[j * 768 + d0];
            u16x8 wv1 = *(const u16x8*)&wh[j * 768 + d0 + 8];
            #pragma unroll
            for (int qq = 0; qq < 8; ++qq) {
                acc[qq]     += aw * bf2f(wv0[qq]);
                acc[8 + qq] += aw * bf2f(wv1[qq]);
            }
        }
        union { u16 s[16]; uint4 u[2]; } o;
        #pragma unroll
        for (int qq = 0; qq < 16; ++qq) {
            float v = acc[qq];
            if (ELU && v < 0.f) v = __expf(v) - 1.0f;
            o.s[qq] = f2bf(v);
        }
        *(uint4*)&Xout[(size_t)b * 10752 + i * 768 + d0]     = o.u[0];
        *(uint4*)&Xout[(size_t)b * 10752 + i * 768 + d0 + 8] = o.u[1];
    }
}

extern "C" void kernel_launch(void* const* d_in, const int* in_sizes, int n_in,
                              void* d_out, int out_size, void* d_ws, size_t ws_size,
                              hipStream_t stream)
{
    const float* features = (const float*)d_in[0];
    const float* adj      = (const float*)d_in[1];
    const float* W_emb    = (const float*)d_in[2];
    const float* b_emb    = (const float*)d_in[3];
    const float* gat_W    = (const float*)d_in[4];
    const float* gat_a    = (const float*)d_in[5];
    const float* W_out    = (const float*)d_in[6];
    const float* b_out    = (const float*)d_in[7];
    float* out = (float*)d_out;

    // ws: Wh (bf16 57344x768) | Wt (5 transposed bf16 mats)
    u16* Wh = (u16*)d_ws;
    u16* Wt = Wh + 44040192;
    // out-region as two bf16 x ping-pong halves until the final GEMM
    u16* H0 = (u16*)d_out;
    u16* H1 = H0 + 44040192;
    float* attn0 = out + 44040192;
    float* attn1 = attn0 + 802816;
    float* attn2 = attn1 + 802816;

    conv_w<<<dim3(720), 256, 0, stream>>>(W_emb, gat_W, W_out, Wt);
    conv_x<<<dim3(4096), 256, 0, stream>>>((const float4*)features, H0, 11010048);

    dim3 gg(2688);
    // x0 = features @ W_emb + b_emb
    gemm_bt<false><<<gg, 256, 0, stream>>>(H0, Wt, b_emb, H1);
    // layer 0
    gemm_bt<false><<<gg, 256, 0, stream>>>(H1, Wt + 589824, nullptr, Wh);
    gat_mix<true><<<dim3(4096), 256, 0, stream>>>(Wh, adj, gat_a, attn0, H0);
    // layer 1
    gemm_bt<false><<<gg, 256, 0, stream>>>(H0, Wt + 2 * 589824, nullptr, Wh);
    gat_mix<true><<<dim3(4096), 256, 0, stream>>>(Wh, adj, gat_a + 1536, attn1, H1);
    // layer 2 (no ELU; x3 in-place over Wh -> staged kernel is safe)
    gemm_bt<false><<<gg, 256, 0, stream>>>(H1, Wt + 3 * 589824, nullptr, Wh);
    gat_mix<false><<<dim3(4096), 256, 0, stream>>>(Wh, adj, gat_a + 3072, attn2, Wh);
    // out = x3 @ W_out + b_out (fp32)
    gemm_bt<true><<<gg, 256, 0, stream>>>(Wh, Wt + 4 * 589824, b_out, (void*)out);
}

// Round 10
// 661.737 us; speedup vs baseline: 1.1255x; 1.0695x over previous
//
#include <hip/hip_runtime.h>

typedef unsigned short u16;
typedef float f32x4 __attribute__((ext_vector_type(4)));
typedef float f32x16 __attribute__((ext_vector_type(16)));
typedef short bf16x8 __attribute__((ext_vector_type(8)));
typedef unsigned short u16x8 __attribute__((ext_vector_type(8)));

#define ND 768
#define KD 768

__device__ __forceinline__ float bf2f(u16 u) {
    union { unsigned i; float f; } v; v.i = ((unsigned)u) << 16; return v.f;
}
__device__ __forceinline__ u16 f2bf(float f) {
    union { float f; unsigned u; } x; x.f = f;
    unsigned r = x.u + 0x7fffu + ((x.u >> 16) & 1u);
    return (u16)(r >> 16);
}
__device__ __forceinline__ void async16(const void* g, void* l) {
    __builtin_amdgcn_global_load_lds((const __attribute__((address_space(1))) void*)g,
                                     (__attribute__((address_space(3))) void*)l, 16, 0, 0);
}

// ---- transpose+convert 5 weights via LDS tiles: Wt[m][n][k] = bf16(W_m[k][n]) ----
__global__ __launch_bounds__(256) void conv_w(const float* __restrict__ W_emb,
                                              const float* __restrict__ gat_W,
                                              const float* __restrict__ W_out,
                                              u16* __restrict__ Wt)
{
    __shared__ float lds[64][65];
    const int m  = blockIdx.x / 144;
    const int r  = blockIdx.x % 144;
    const int tr = r / 12;
    const int tc = r % 12;
    const float* src = (m == 0) ? W_emb : (m <= 3) ? (gat_W + (size_t)(m - 1) * 589824) : W_out;
    const int c  = threadIdx.x & 63;
    const int w4 = threadIdx.x >> 6;
    #pragma unroll
    for (int i = 0; i < 16; ++i) {
        int kk = i * 4 + w4;
        lds[kk][c] = src[(size_t)(tr * 64 + kk) * 768 + tc * 64 + c];
    }
    __syncthreads();
    u16* dst = Wt + (size_t)m * 589824;
    #pragma unroll
    for (int i = 0; i < 16; ++i) {
        int nn = i * 4 + w4;
        dst[(size_t)(tc * 64 + nn) * 768 + tr * 64 + c] = f2bf(lds[c][nn]);
    }
}

// ---- single-matrix variant (144 blocks): dst[n][k] = bf16(src[k][n]) ----
__global__ __launch_bounds__(256) void conv_w1(const float* __restrict__ src,
                                               u16* __restrict__ dst)
{
    __shared__ float lds[64][65];
    const int r  = blockIdx.x;
    const int tr = r / 12;
    const int tc = r % 12;
    const int c  = threadIdx.x & 63;
    const int w4 = threadIdx.x >> 6;
    #pragma unroll
    for (int i = 0; i < 16; ++i) {
        int kk = i * 4 + w4;
        lds[kk][c] = src[(size_t)(tr * 64 + kk) * 768 + tc * 64 + c];
    }
    __syncthreads();
    #pragma unroll
    for (int i = 0; i < 16; ++i) {
        int nn = i * 4 + w4;
        dst[(size_t)(tc * 64 + nn) * 768 + tr * 64 + c] = f2bf(lds[c][nn]);
    }
}

// ---- fp32 -> bf16 bulk convert ----
__global__ __launch_bounds__(256) void conv_x(const float4* __restrict__ in,
                                              u16* __restrict__ outp, int n4)
{
    for (int i = blockIdx.x * 256 + threadIdx.x; i < n4; i += gridDim.x * 256) {
        float4 v = in[i];
        union { u16 s[4]; uint2 u; } o;
        o.s[0] = f2bf(v.x); o.s[1] = f2bf(v.y); o.s[2] = f2bf(v.z); o.s[3] = f2bf(v.w);
        ((uint2*)outp)[i] = o.u;
    }
}

// ---- tiny precompute: w3ai[k]=W3[k]:·a_i, w3aj[k]=W3[k]:·a_j, bfus[n]=be·W1[:,n] ----
__global__ __launch_bounds__(256) void prep_vecs(const float* __restrict__ W3,
                                                 const float* __restrict__ ga2,
                                                 const float* __restrict__ be,
                                                 const u16* __restrict__ Wt1,
                                                 float* __restrict__ w3ai,
                                                 float* __restrict__ w3aj,
                                                 float* __restrict__ bfus)
{
    int d = blockIdx.x * 256 + threadIdx.x;
    if (d >= 768) return;
    const float* row = W3 + (size_t)d * 768;
    float ai = 0.f, aj = 0.f;
    for (int n = 0; n < 768; ++n) { float w = row[n]; ai += w * ga2[n]; aj += w * ga2[768 + n]; }
    w3ai[d] = ai; w3aj[d] = aj;
    const u16* wt = Wt1 + (size_t)d * 768;
    float bf = 0.f;
    for (int j = 0; j < 768; ++j) bf += be[j] * bf2f(wt[j]);
    bfus[d] = bf;
}

// ---- bf16 GEMM, 2-phase double-buffered prefetch + 32x32x16 MFMA (R9 body) ----
template<bool F32OUT, bool SWZ>
__global__ __launch_bounds__(256) void gemm_bt(const u16* __restrict__ A,
                                               const u16* __restrict__ Bt,
                                               const float* __restrict__ bias,
                                               void* __restrict__ Cout)
{
    __shared__ u16 lds2[2][2][4096];
    const int tid  = threadIdx.x;
    const int lane = tid & 63;
    const int wvb  = tid & ~63;
    const int wm   = ((tid >> 7) & 1) * 64;
    const int wn   = ((tid >> 6) & 1) * 64;
    const int wg = blockIdx.x;
    const int id = SWZ ? ((wg & 7) * 336 + (wg >> 3)) : wg;
    const int tn = (id % 6) * 128;
    const int tm = (id / 6) * 128;

    f32x16 acc[2][2] = {};

    const int r31 = lane & 31;
    const int l5  = lane >> 5;
    const int key = (r31 >> 1) & 3;

    const int row0 = tid >> 2;
    const int kc0  = (((tid & 3) ^ ((tid >> 3) & 3)) << 3);
    const u16* aSrc = A  + (size_t)(tm + row0) * KD + kc0;
    const u16* bSrc = Bt + (size_t)(tn + row0) * KD + kc0;

    #define STAGE(b, ks_) { const int k0 = (ks_) * 32;                      \
        async16(aSrc + k0,                  &lds2[b][0][wvb * 8]);          \
        async16(aSrc + (size_t)64 * KD + k0, &lds2[b][0][(256 + wvb) * 8]); \
        async16(bSrc + k0,                  &lds2[b][1][wvb * 8]);          \
        async16(bSrc + (size_t)64 * KD + k0, &lds2[b][1][(256 + wvb) * 8]); }

    STAGE(0, 0);

    #pragma unroll 2
    for (int ks = 0; ks < KD / 32; ++ks) {
        const int cur = ks & 1;
        if (ks + 1 < KD / 32) {
            STAGE(cur ^ 1, ks + 1);
            asm volatile("s_waitcnt vmcnt(4)" ::: "memory");
        } else {
            asm volatile("s_waitcnt vmcnt(0)" ::: "memory");
        }
        __builtin_amdgcn_s_barrier();
        asm volatile("" ::: "memory");

        const u16* As = lds2[cur][0];
        const u16* Bs = lds2[cur][1];
        bf16x8 af[2][2], bf[2][2];
        #pragma unroll
        for (int fr = 0; fr < 2; ++fr)
            #pragma unroll
            for (int ka = 0; ka < 2; ++ka) {
                int chA = ((ka * 2 + l5) ^ key) << 3;
                af[fr][ka] = *(const bf16x8*)&As[(wm + fr * 32 + r31) * 32 + chA];
                bf[fr][ka] = *(const bf16x8*)&Bs[(wn + fr * 32 + r31) * 32 + chA];
            }
        #pragma unroll
        for (int fr = 0; fr < 2; ++fr)
            #pragma unroll
            for (int fc = 0; fc < 2; ++fc)
                #pragma unroll
                for (int ka = 0; ka < 2; ++ka)
                    acc[fr][fc] = __builtin_amdgcn_mfma_f32_32x32x16_bf16(
                        af[fr][ka], bf[fc][ka], acc[fr][fc], 0, 0, 0);

        if (ks + 1 < KD / 32) {
            asm volatile("" ::: "memory");
            __builtin_amdgcn_s_barrier();
        }
    }
    #undef STAGE

    // epilogue: 32x32 C/D layout col=lane&31, row=(reg&3)+8*(reg>>2)+4*(lane>>5)
    #pragma unroll
    for (int fc = 0; fc < 2; ++fc) {
        int col = tn + wn + fc * 32 + r31;
        float bv = bias ? bias[col] : 0.0f;
        #pragma unroll
        for (int fr = 0; fr < 2; ++fr) {
            int rowb = tm + wm + fr * 32 + 4 * l5;
            #pragma unroll
            for (int reg = 0; reg < 16; ++reg) {
                int row = rowb + (reg & 3) + 8 * (reg >> 2);
                float v = acc[fr][fc][reg] + bv;
                if (F32OUT)
                    ((float*)Cout)[(size_t)row * ND + col] = v;
                else
                    ((u16*)Cout)[(size_t)row * ND + col] = f2bf(v);
            }
        }
    }
}

// ---- fused GAT attention: ei/ej from staged Wh, softmax, mix, ELU ----
// DOTS: also accumulate ei3/ej3 = x_next · w3ai/w3aj for the final layer.
template<bool ELU, bool DOTS>
__global__ __launch_bounds__(256) void gat_mix(const u16* __restrict__ Wh,
                                               const float* __restrict__ adj,
                                               const float* __restrict__ avec,
                                               float* __restrict__ attn_out,
                                               u16* __restrict__ Xout,
                                               const float* __restrict__ w3ai,
                                               const float* __restrict__ w3aj,
                                               float* __restrict__ eiOut,
                                               float* __restrict__ ejOut)
{
    __shared__ u16 wh[14 * 768];
    __shared__ float s_ei[14], s_ej[14];
    __shared__ float s_attn[196];
    __shared__ float s_dots[14][2];
    const int b = blockIdx.x;
    const int tid = threadIdx.x;
    const u16* whb = Wh + (size_t)b * 10752;

    if (DOTS && tid < 28) ((float*)s_dots)[tid] = 0.f;
    for (int c = tid; c < 1344; c += 256)
        ((uint4*)wh)[c] = ((const uint4*)whb)[c];
    __syncthreads();

    // ei/ej: 14 rows x 16 lanes
    if (tid < 224) {
        const int i = tid >> 4, l = tid & 15;
        float ai = 0.f, aj = 0.f;
        #pragma unroll
        for (int c = 0; c < 6; ++c) {
            int d = c * 128 + l * 8;
            u16x8 v  = *(const u16x8*)&wh[i * 768 + d];
            float4 x0 = *(const float4*)&avec[d];
            float4 x1 = *(const float4*)&avec[d + 4];
            float4 y0 = *(const float4*)&avec[768 + d];
            float4 y1 = *(const float4*)&avec[768 + d + 4];
            float w0 = bf2f(v[0]), w1 = bf2f(v[1]), w2 = bf2f(v[2]), w3 = bf2f(v[3]);
            float w4 = bf2f(v[4]), w5 = bf2f(v[5]), w6 = bf2f(v[6]), w7 = bf2f(v[7]);
            ai += w0*x0.x + w1*x0.y + w2*x0.z + w3*x0.w + w4*x1.x + w5*x1.y + w6*x1.z + w7*x1.w;
            aj += w0*y0.x + w1*y0.y + w2*y0.z + w3*y0.w + w4*y1.x + w5*y1.y + w6*y1.z + w7*y1.w;
        }
        #pragma unroll
        for (int off = 8; off; off >>= 1) {
            ai += __shfl_xor(ai, off);
            aj += __shfl_xor(aj, off);
        }
        if (l == 0) { s_ei[i] = ai; s_ej[i] = aj; }
    }
    __syncthreads();

    if (tid < 14) {
        const int i = tid;
        float e[14];
        float mx = -3.0e38f;
        #pragma unroll
        for (int j = 0; j < 14; ++j) {
            float ev = (adj[(size_t)b * 196 + i * 14 + j] > 0.f) ? (s_ei[i] + s_ej[j]) : -1.0e30f;
            e[j] = ev; mx = fmaxf(mx, ev);
        }
        float sum = 0.f;
        #pragma unroll
        for (int j = 0; j < 14; ++j) { float pp = __expf(e[j] - mx); e[j] = pp; sum += pp; }
        float inv = 1.0f / sum;
        #pragma unroll
        for (int j = 0; j < 14; ++j) s_attn[i * 14 + j] = e[j] * inv;
    }
    __syncthreads();

    if (tid < 196) attn_out[(size_t)b * 196 + tid] = s_attn[tid];

    for (int pp = tid; pp < 14 * 48; pp += 256) {
        const int i  = pp / 48;
        const int d0 = (pp % 48) * 16;
        float acc[16] = {};
        #pragma unroll
        for (int j = 0; j < 14; ++j) {
            float aw = s_attn[i * 14 + j];
            u16x8 wv0 = *(const u16x8*)&wh[j * 768 + d0];
            u16x8 wv1 = *(const u16x8*)&wh[j * 768 + d0 + 8];
            #pragma unroll
            for (int qq = 0; qq < 8; ++qq) {
                acc[qq]     += aw * bf2f(wv0[qq]);
                acc[8 + qq] += aw * bf2f(wv1[qq]);
            }
        }
        float pi = 0.f, pj = 0.f;
        union { u16 s[16]; uint4 u[2]; } o;
        #pragma unroll
        for (int qq = 0; qq < 16; ++qq) {
            float v = acc[qq];
            if (ELU && v < 0.f) v = __expf(v) - 1.0f;
            if (DOTS) { pi += v * w3ai[d0 + qq]; pj += v * w3aj[d0 + qq]; }
            o.s[qq] = f2bf(v);
        }
        if (DOTS) {
            atomicAdd(&s_dots[i][0], pi);
            atomicAdd(&s_dots[i][1], pj);
        }
        *(uint4*)&Xout[(size_t)b * 10752 + i * 768 + d0]     = o.u[0];
        *(uint4*)&Xout[(size_t)b * 10752 + i * 768 + d0 + 8] = o.u[1];
    }
    if (DOTS) {
        __syncthreads();
        if (tid < 14) {
            eiOut[(size_t)b * 14 + tid] = s_dots[tid][0];
            ejOut[(size_t)b * 14 + tid] = s_dots[tid][1];
        }
    }
}

// ---- final layer: softmax from precomputed ei3/ej3, out = attn2 @ Z + b_out ----
__global__ __launch_bounds__(256) void gat_out(const u16* __restrict__ Z,
                                               const float* __restrict__ adj,
                                               const float* __restrict__ eiG,
                                               const float* __restrict__ ejG,
                                               const float* __restrict__ b_out,
                                               float* __restrict__ attn_out,
                                               float* __restrict__ outp)
{
    __shared__ u16 wh[14 * 768];
    __shared__ float s_attn[196];
    const int b = blockIdx.x;
    const int tid = threadIdx.x;
    const u16* zb = Z + (size_t)b * 10752;

    for (int c = tid; c < 1344; c += 256)
        ((uint4*)wh)[c] = ((const uint4*)zb)[c];

    if (tid < 14) {
        const int i = tid;
        float ei = eiG[(size_t)b * 14 + i];
        float e[14];
        float mx = -3.0e38f;
        #pragma unroll
        for (int j = 0; j < 14; ++j) {
            float ev = (adj[(size_t)b * 196 + i * 14 + j] > 0.f)
                           ? (ei + ejG[(size_t)b * 14 + j]) : -1.0e30f;
            e[j] = ev; mx = fmaxf(mx, ev);
        }
        float sum = 0.f;
        #pragma unroll
        for (int j = 0; j < 14; ++j) { float pp = __expf(e[j] - mx); e[j] = pp; sum += pp; }
        float inv = 1.0f / sum;
        #pragma unroll
        for (int j = 0; j < 14; ++j) s_attn[i * 14 + j] = e[j] * inv;
    }
    __syncthreads();

    if (tid < 196) attn_out[(size_t)b * 196 + tid] = s_attn[tid];

    for (int pp = tid; pp < 14 * 48; pp += 256) {
        const int i  = pp / 48;
        const int d0 = (pp % 48) * 16;
        float acc[16];
        #pragma unroll
        for (int qq = 0; qq < 16; ++qq) acc[qq] = b_out[d0 + qq];
        #pragma unroll
        for (int j = 0; j < 14; ++j) {
            float aw = s_attn[i * 14 + j];
            u16x8 wv0 = *(const u16x8*)&wh[j * 768 + d0];
            u16x8 wv1 = *(const u16x8*)&wh[j * 768 + d0 + 8];
            #pragma unroll
            for (int qq = 0; qq < 8; ++qq) {
                acc[qq]     += aw * bf2f(wv0[qq]);
                acc[8 + qq] += aw * bf2f(wv1[qq]);
            }
        }
        float* dst = &outp[(size_t)b * 10752 + i * 768 + d0];
        *(float4*)(dst)      = *(float4*)&acc[0];
        *(float4*)(dst + 4)  = *(float4*)&acc[4];
        *(float4*)(dst + 8)  = *(float4*)&acc[8];
        *(float4*)(dst + 12) = *(float4*)&acc[12];
    }
}

extern "C" void kernel_launch(void* const* d_in, const int* in_sizes, int n_in,
                              void* d_out, int out_size, void* d_ws, size_t ws_size,
                              hipStream_t stream)
{
    const float* features = (const float*)d_in[0];
    const float* adj      = (const float*)d_in[1];
    const float* W_emb    = (const float*)d_in[2];
    const float* b_emb    = (const float*)d_in[3];
    const float* gat_W    = (const float*)d_in[4];
    const float* gat_a    = (const float*)d_in[5];
    const float* W_out    = (const float*)d_in[6];
    const float* b_out    = (const float*)d_in[7];
    float* out = (float*)d_out;

    // ws: Wh (bf16 57344x768) | Wt[7] (5 orig + 2 fused) | scr f32 768^2 | vecs | ei/ej
    u16* Wh = (u16*)d_ws;
    u16* Wt = Wh + 44040192;
    float* scr  = (float*)(Wt + 7 * 589824);
    float* w3ai = scr + 589824;
    float* w3aj = w3ai + 768;
    float* bfus = w3aj + 768;
    float* eiG  = bfus + 768;
    float* ejG  = eiG + 57344;
    // out-region: two bf16 x ping-pong halves + bf16 staging for We/W3 copies
    u16* H0 = (u16*)d_out;
    u16* H1 = H0 + 44040192;
    u16* WeBf = H1;                 // dead before H1 is first written (mix0)
    u16* W3Bf = H1 + 589824;
    float* attn0 = out + 44040192;
    float* attn1 = attn0 + 802816;
    float* attn2 = attn1 + 802816;

    // weight prep
    conv_w<<<dim3(720), 256, 0, stream>>>(W_emb, gat_W, W_out, Wt);
    conv_x<<<dim3(4096), 256, 0, stream>>>((const float4*)features, H0, 11010048);
    conv_x<<<dim3(576), 256, 0, stream>>>((const float4*)W_emb, WeBf, 147456);
    conv_x<<<dim3(576), 256, 0, stream>>>((const float4*)(gat_W + 2 * 589824), W3Bf, 147456);
    prep_vecs<<<dim3(3), 256, 0, stream>>>(gat_W + 2 * 589824, gat_a + 2 * 1536, b_emb,
                                           Wt + 589824, w3ai, w3aj, bfus);
    // WfA = We@W1 -> Wt[5];  WfC = W3@W_out -> Wt[6]
    gemm_bt<true, false><<<dim3(36), 256, 0, stream>>>(WeBf, Wt + 1 * 589824, nullptr, scr);
    conv_w1<<<dim3(144), 256, 0, stream>>>(scr, Wt + 5 * 589824);
    gemm_bt<true, false><<<dim3(36), 256, 0, stream>>>(W3Bf, Wt + 4 * 589824, nullptr, scr);
    conv_w1<<<dim3(144), 256, 0, stream>>>(scr, Wt + 6 * 589824);

    dim3 gg(2688);
    // layer 0 (embed fused): Wh1 = f @ (We*W1) + be*W1
    gemm_bt<false, true><<<gg, 256, 0, stream>>>(H0, Wt + 5 * 589824, bfus, Wh);
    gat_mix<true, false><<<dim3(4096), 256, 0, stream>>>(Wh, adj, gat_a, attn0, H1,
                                                         nullptr, nullptr, nullptr, nullptr);
    // layer 1: Wh2 = x1 @ W2 ; mix also emits ei3/ej3 = x2 . (W3 a_i/j)
    gemm_bt<false, true><<<gg, 256, 0, stream>>>(H1, Wt + 2 * 589824, nullptr, Wh);
    gat_mix<true, true><<<dim3(4096), 256, 0, stream>>>(Wh, adj, gat_a + 1536, attn1, H0,
                                                        w3ai, w3aj, eiG, ejG);
    // layer 2 + out-proj fused: Z = x2 @ (W3*W_out); out = attn2 @ Z + b_out
    gemm_bt<false, true><<<gg, 256, 0, stream>>>(H0, Wt + 6 * 589824, nullptr, Wh);
    gat_out<<<dim3(4096), 256, 0, stream>>>(Wh, adj, eiG, ejG, b_out, attn2, out);
}

// Round 11
// 659.874 us; speedup vs baseline: 1.1287x; 1.0028x over previous
//
#include <hip/hip_runtime.h>

typedef unsigned short u16;
typedef float f32x4 __attribute__((ext_vector_type(4)));
typedef float f32x16 __attribute__((ext_vector_type(16)));
typedef short bf16x8 __attribute__((ext_vector_type(8)));
typedef unsigned short u16x8 __attribute__((ext_vector_type(8)));

#define ND 768
#define KD 768

__device__ __forceinline__ float bf2f(u16 u) {
    union { unsigned i; float f; } v; v.i = ((unsigned)u) << 16; return v.f;
}
__device__ __forceinline__ u16 f2bf(float f) {
    union { float f; unsigned u; } x; x.f = f;
    unsigned r = x.u + 0x7fffu + ((x.u >> 16) & 1u);
    return (u16)(r >> 16);
}
__device__ __forceinline__ void async16(const void* g, void* l) {
    __builtin_amdgcn_global_load_lds((const __attribute__((address_space(1))) void*)g,
                                     (__attribute__((address_space(3))) void*)l, 16, 0, 0);
}

// ---- transpose+convert 5 weights via LDS tiles: Wt[m][n][k] = bf16(W_m[k][n]) ----
__global__ __launch_bounds__(256) void conv_w(const float* __restrict__ W_emb,
                                              const float* __restrict__ gat_W,
                                              const float* __restrict__ W_out,
                                              u16* __restrict__ Wt)
{
    __shared__ float lds[64][65];
    const int m  = blockIdx.x / 144;
    const int r  = blockIdx.x % 144;
    const int tr = r / 12;
    const int tc = r % 12;
    const float* src = (m == 0) ? W_emb : (m <= 3) ? (gat_W + (size_t)(m - 1) * 589824) : W_out;
    const int c  = threadIdx.x & 63;
    const int w4 = threadIdx.x >> 6;
    #pragma unroll
    for (int i = 0; i < 16; ++i) {
        int kk = i * 4 + w4;
        lds[kk][c] = src[(size_t)(tr * 64 + kk) * 768 + tc * 64 + c];
    }
    __syncthreads();
    u16* dst = Wt + (size_t)m * 589824;
    #pragma unroll
    for (int i = 0; i < 16; ++i) {
        int nn = i * 4 + w4;
        dst[(size_t)(tc * 64 + nn) * 768 + tr * 64 + c] = f2bf(lds[c][nn]);
    }
}

// ---- transpose both halves of scr (1536x768 fp32) into Wt5, Wt6 (bf16 K-major) ----
__global__ __launch_bounds__(256) void conv_w2(const float* __restrict__ src0,
                                               u16* __restrict__ dst0)
{
    __shared__ float lds[64][65];
    const int m  = blockIdx.x / 144;          // 0: We*W1, 1: W3*Wout
    const int r  = blockIdx.x % 144;
    const int tr = r / 12;
    const int tc = r % 12;
    const float* src = src0 + (size_t)m * 589824;
    u16* dst = dst0 + (size_t)m * 589824;
    const int c  = threadIdx.x & 63;
    const int w4 = threadIdx.x >> 6;
    #pragma unroll
    for (int i = 0; i < 16; ++i) {
        int kk = i * 4 + w4;
        lds[kk][c] = src[(size_t)(tr * 64 + kk) * 768 + tc * 64 + c];
    }
    __syncthreads();
    #pragma unroll
    for (int i = 0; i < 16; ++i) {
        int nn = i * 4 + w4;
        dst[(size_t)(tc * 64 + nn) * 768 + tr * 64 + c] = f2bf(lds[c][nn]);
    }
}

// ---- fp32 -> bf16 bulk convert ----
__global__ __launch_bounds__(256) void conv_x(const float4* __restrict__ in,
                                              u16* __restrict__ outp, int n4)
{
    for (int i = blockIdx.x * 256 + threadIdx.x; i < n4; i += gridDim.x * 256) {
        float4 v = in[i];
        union { u16 s[4]; uint2 u; } o;
        o.s[0] = f2bf(v.x); o.s[1] = f2bf(v.y); o.s[2] = f2bf(v.z); o.s[3] = f2bf(v.w);
        ((uint2*)outp)[i] = o.u;
    }
}

// ---- tiny precompute: w3ai[k]=W3[k]:·a_i, w3aj[k]=W3[k]:·a_j, bfus[n]=be·W1[:,n] ----
__global__ __launch_bounds__(256) void prep_vecs(const float* __restrict__ W3,
                                                 const float* __restrict__ ga2,
                                                 const float* __restrict__ be,
                                                 const u16* __restrict__ Wt1,
                                                 float* __restrict__ w3ai,
                                                 float* __restrict__ w3aj,
                                                 float* __restrict__ bfus)
{
    int d = blockIdx.x * 256 + threadIdx.x;
    if (d >= 768) return;
    const float* row = W3 + (size_t)d * 768;
    float ai = 0.f, aj = 0.f;
    for (int n = 0; n < 768; ++n) { float w = row[n]; ai += w * ga2[n]; aj += w * ga2[768 + n]; }
    w3ai[d] = ai; w3aj[d] = aj;
    const u16* wt = Wt1 + (size_t)d * 768;
    float bf = 0.f;
    for (int j = 0; j < 768; ++j) bf += be[j] * bf2f(wt[j]);
    bfus[d] = bf;
}

// ---- bf16 GEMM, 2-phase double-buffered prefetch + 32x32x16 MFMA ----
// A32: A is fp32, reg-staged (global->reg issued a tile ahead, converted,
// ds_write into the SAME linear LDS layout as the gload_lds path).
// Bt2: optional second B selected when tm>=768 (stacked prep GEMM).
template<bool F32OUT, bool SWZ, bool A32>
__global__ __launch_bounds__(256) void gemm_bt(const void* __restrict__ Ain,
                                               const u16* __restrict__ Bt,
                                               const u16* __restrict__ Bt2,
                                               const float* __restrict__ bias,
                                               void* __restrict__ Cout)
{
    __shared__ u16 lds2[2][2][4096];
    const int tid  = threadIdx.x;
    const int lane = tid & 63;
    const int wvb  = tid & ~63;
    const int wm   = ((tid >> 7) & 1) * 64;
    const int wn   = ((tid >> 6) & 1) * 64;
    const int wg = blockIdx.x;
    const int id = SWZ ? ((wg & 7) * 336 + (wg >> 3)) : wg;
    const int tn = (id % 6) * 128;
    const int tm = (id / 6) * 128;
    const u16* BtU = (Bt2 != nullptr && tm >= 768) ? Bt2 : Bt;

    f32x16 acc[2][2] = {};

    const int r31 = lane & 31;
    const int l5  = lane >> 5;
    const int key = (r31 >> 1) & 3;

    const int row0 = tid >> 2;
    const int kc0  = (((tid & 3) ^ ((tid >> 3) & 3)) << 3);
    const u16*   aS16 = (const u16*)Ain  + (size_t)(tm + row0) * KD + kc0;
    const float* aS32 = (const float*)Ain + (size_t)(tm + row0) * KD + kc0;
    const u16*   bSrc = BtU + (size_t)(tn + row0) * KD + kc0;

    #define STAGE_B16(b, ks_) { const int k0 = (ks_) * 32;                   \
        async16(bSrc + k0,                   &lds2[b][1][wvb * 8]);          \
        async16(bSrc + (size_t)64 * KD + k0, &lds2[b][1][(256 + wvb) * 8]); }
    #define STAGE_A16(b, ks_) { const int k0 = (ks_) * 32;                   \
        async16(aS16 + k0,                   &lds2[b][0][wvb * 8]);          \
        async16(aS16 + (size_t)64 * KD + k0, &lds2[b][0][(256 + wvb) * 8]); }
    #define LOADA32(ks_) { const int k0 = (ks_) * 32;                        \
        ar0 = *(const float4*)(aS32 + k0);                                   \
        ar1 = *(const float4*)(aS32 + k0 + 4);                               \
        ar2 = *(const float4*)(aS32 + (size_t)64 * KD + k0);                 \
        ar3 = *(const float4*)(aS32 + (size_t)64 * KD + k0 + 4); }
    #define WRA32(b) { union { u16 s[8]; uint4 u; } p0, p1;                  \
        p0.s[0]=f2bf(ar0.x); p0.s[1]=f2bf(ar0.y); p0.s[2]=f2bf(ar0.z); p0.s[3]=f2bf(ar0.w); \
        p0.s[4]=f2bf(ar1.x); p0.s[5]=f2bf(ar1.y); p0.s[6]=f2bf(ar1.z); p0.s[7]=f2bf(ar1.w); \
        p1.s[0]=f2bf(ar2.x); p1.s[1]=f2bf(ar2.y); p1.s[2]=f2bf(ar2.z); p1.s[3]=f2bf(ar2.w); \
        p1.s[4]=f2bf(ar3.x); p1.s[5]=f2bf(ar3.y); p1.s[6]=f2bf(ar3.z); p1.s[7]=f2bf(ar3.w); \
        *(uint4*)&lds2[b][0][(size_t)tid * 8]         = p0.u;                \
        *(uint4*)&lds2[b][0][(size_t)(256 + tid) * 8] = p1.u; }

    float4 ar0, ar1, ar2, ar3;

    // prologue: fill buf 0
    if (A32) {
        LOADA32(0);
        STAGE_B16(0, 0);
        asm volatile("s_waitcnt vmcnt(2)" ::: "memory");   // A-regs landed
        WRA32(0);
    } else {
        STAGE_A16(0, 0);
        STAGE_B16(0, 0);
    }

    #pragma unroll 2
    for (int ks = 0; ks < KD / 32; ++ks) {
        const int cur = ks & 1;
        if (ks + 1 < KD / 32) {
            if (A32) {
                LOADA32(ks + 1);                            // 4 vm loads (regs)
                STAGE_B16(cur ^ 1, ks + 1);                 // 2 vm -> LDS
                asm volatile("s_waitcnt vmcnt(6)" ::: "memory");  // B(t) landed
            } else {
                STAGE_A16(cur ^ 1, ks + 1);
                STAGE_B16(cur ^ 1, ks + 1);
                asm volatile("s_waitcnt vmcnt(4)" ::: "memory");  // buf cur landed
            }
        } else {
            asm volatile("s_waitcnt vmcnt(0)" ::: "memory");
        }
        if (A32) asm volatile("s_waitcnt lgkmcnt(0)" ::: "memory"); // my ds_writes of cur done
        __builtin_amdgcn_s_barrier();
        asm volatile("" ::: "memory");

        const u16* As = lds2[cur][0];
        const u16* Bs = lds2[cur][1];
        bf16x8 af[2][2], bf[2][2];
        #pragma unroll
        for (int fr = 0; fr < 2; ++fr)
            #pragma unroll
            for (int ka = 0; ka < 2; ++ka) {
                int chA = ((ka * 2 + l5) ^ key) << 3;
                af[fr][ka] = *(const bf16x8*)&As[(wm + fr * 32 + r31) * 32 + chA];
                bf[fr][ka] = *(const bf16x8*)&Bs[(wn + fr * 32 + r31) * 32 + chA];
            }
        #pragma unroll
        for (int fr = 0; fr < 2; ++fr)
            #pragma unroll
            for (int fc = 0; fc < 2; ++fc)
                #pragma unroll
                for (int ka = 0; ka < 2; ++ka)
                    acc[fr][fc] = __builtin_amdgcn_mfma_f32_32x32x16_bf16(
                        af[fr][ka], bf[fc][ka], acc[fr][fc], 0, 0, 0);

        if (ks + 1 < KD / 32) {
            if (A32) {
                asm volatile("s_waitcnt vmcnt(2)" ::: "memory");  // A-regs(t+1) landed
                WRA32(cur ^ 1);                                    // write next A
            }
            asm volatile("" ::: "memory");
            __builtin_amdgcn_s_barrier();     // protect bufs from next iter's stages
            asm volatile("" ::: "memory");
        }
    }
    #undef STAGE_A16
    #undef STAGE_B16
    #undef LOADA32
    #undef WRA32

    // epilogue: 32x32 C/D layout col=lane&31, row=(reg&3)+8*(reg>>2)+4*(lane>>5)
    #pragma unroll
    for (int fc = 0; fc < 2; ++fc) {
        int col = tn + wn + fc * 32 + r31;
        float bv = bias ? bias[col] : 0.0f;
        #pragma unroll
        for (int fr = 0; fr < 2; ++fr) {
            int rowb = tm + wm + fr * 32 + 4 * l5;
            #pragma unroll
            for (int reg = 0; reg < 16; ++reg) {
                int row = rowb + (reg & 3) + 8 * (reg >> 2);
                float v = acc[fr][fc][reg] + bv;
                if (F32OUT)
                    ((float*)Cout)[(size_t)row * ND + col] = v;
                else
                    ((u16*)Cout)[(size_t)row * ND + col] = f2bf(v);
            }
        }
    }
}

// ---- fused GAT attention: ei/ej from staged Wh, softmax, mix, ELU ----
template<bool ELU, bool DOTS>
__global__ __launch_bounds__(256) void gat_mix(const u16* __restrict__ Wh,
                                               const float* __restrict__ adj,
                                               const float* __restrict__ avec,
                                               float* __restrict__ attn_out,
                                               u16* __restrict__ Xout,
                                               const float* __restrict__ w3ai,
                                               const float* __restrict__ w3aj,
                                               float* __restrict__ eiOut,
                                               float* __restrict__ ejOut)
{
    __shared__ u16 wh[14 * 768];
    __shared__ float s_ei[14], s_ej[14];
    __shared__ float s_attn[196];
    __shared__ float s_dots[14][2];
    const int b = blockIdx.x;
    const int tid = threadIdx.x;
    const u16* whb = Wh + (size_t)b * 10752;

    if (DOTS && tid < 28) ((float*)s_dots)[tid] = 0.f;
    for (int c = tid; c < 1344; c += 256)
        ((uint4*)wh)[c] = ((const uint4*)whb)[c];
    __syncthreads();

    if (tid < 224) {
        const int i = tid >> 4, l = tid & 15;
        float ai = 0.f, aj = 0.f;
        #pragma unroll
        for (int c = 0; c < 6; ++c) {
            int d = c * 128 + l * 8;
            u16x8 v  = *(const u16x8*)&wh[i * 768 + d];
            float4 x0 = *(const float4*)&avec[d];
            float4 x1 = *(const float4*)&avec[d + 4];
            float4 y0 = *(const float4*)&avec[768 + d];
            float4 y1 = *(const float4*)&avec[768 + d + 4];
            float w0 = bf2f(v[0]), w1 = bf2f(v[1]), w2 = bf2f(v[2]), w3 = bf2f(v[3]);
            float w4 = bf2f(v[4]), w5 = bf2f(v[5]), w6 = bf2f(v[6]), w7 = bf2f(v[7]);
            ai += w0*x0.x + w1*x0.y + w2*x0.z + w3*x0.w + w4*x1.x + w5*x1.y + w6*x1.z + w7*x1.w;
            aj += w0*y0.x + w1*y0.y + w2*y0.z + w3*y0.w + w4*y1.x + w5*y1.y + w6*y1.z + w7*y1.w;
        }
        #pragma unroll
        for (int off = 8; off; off >>= 1) {
            ai += __shfl_xor(ai, off);
            aj += __shfl_xor(aj, off);
        }
        if (l == 0) { s_ei[i] = ai; s_ej[i] = aj; }
    }
    __syncthreads();

    if (tid < 14) {
        const int i = tid;
        float e[14];
        float mx = -3.0e38f;
        #pragma unroll
        for (int j = 0; j < 14; ++j) {
            float ev = (adj[(size_t)b * 196 + i * 14 + j] > 0.f) ? (s_ei[i] + s_ej[j]) : -1.0e30f;
            e[j] = ev; mx = fmaxf(mx, ev);
        }
        float sum = 0.f;
        #pragma unroll
        for (int j = 0; j < 14; ++j) { float pp = __expf(e[j] - mx); e[j] = pp; sum += pp; }
        float inv = 1.0f / sum;
        #pragma unroll
        for (int j = 0; j < 14; ++j) s_attn[i * 14 + j] = e[j] * inv;
    }
    __syncthreads();

    if (tid < 196) attn_out[(size_t)b * 196 + tid] = s_attn[tid];

    for (int pp = tid; pp < 14 * 48; pp += 256) {
        const int i  = pp / 48;
        const int d0 = (pp % 48) * 16;
        float acc[16] = {};
        #pragma unroll
        for (int j = 0; j < 14; ++j) {
            float aw = s_attn[i * 14 + j];
            u16x8 wv0 = *(const u16x8*)&wh[j * 768 + d0];
            u16x8 wv1 = *(const u16x8*)&wh[j * 768 + d0 + 8];
            #pragma unroll
            for (int qq = 0; qq < 8; ++qq) {
                acc[qq]     += aw * bf2f(wv0[qq]);
                acc[8 + qq] += aw * bf2f(wv1[qq]);
            }
        }
        float pi = 0.f, pj = 0.f;
        union { u16 s[16]; uint4 u[2]; } o;
        #pragma unroll
        for (int qq = 0; qq < 16; ++qq) {
            float v = acc[qq];
            if (ELU && v < 0.f) v = __expf(v) - 1.0f;
            if (DOTS) { pi += v * w3ai[d0 + qq]; pj += v * w3aj[d0 + qq]; }
            o.s[qq] = f2bf(v);
        }
        if (DOTS) {
            atomicAdd(&s_dots[i][0], pi);
            atomicAdd(&s_dots[i][1], pj);
        }
        *(uint4*)&Xout[(size_t)b * 10752 + i * 768 + d0]     = o.u[0];
        *(uint4*)&Xout[(size_t)b * 10752 + i * 768 + d0 + 8] = o.u[1];
    }
    if (DOTS) {
        __syncthreads();
        if (tid < 14) {
            eiOut[(size_t)b * 14 + tid] = s_dots[tid][0];
            ejOut[(size_t)b * 14 + tid] = s_dots[tid][1];
        }
    }
}

// ---- final layer: softmax from precomputed ei3/ej3, out = attn2 @ Z + b_out ----
__global__ __launch_bounds__(256) void gat_out(const u16* __restrict__ Z,
                                               const float* __restrict__ adj,
                                               const float* __restrict__ eiG,
                                               const float* __restrict__ ejG,
                                               const float* __restrict__ b_out,
                                               float* __restrict__ attn_out,
                                               float* __restrict__ outp)
{
    __shared__ u16 wh[14 * 768];
    __shared__ float s_attn[196];
    const int b = blockIdx.x;
    const int tid = threadIdx.x;
    const u16* zb = Z + (size_t)b * 10752;

    for (int c = tid; c < 1344; c += 256)
        ((uint4*)wh)[c] = ((const uint4*)zb)[c];

    if (tid < 14) {
        const int i = tid;
        float ei = eiG[(size_t)b * 14 + i];
        float e[14];
        float mx = -3.0e38f;
        #pragma unroll
        for (int j = 0; j < 14; ++j) {
            float ev = (adj[(size_t)b * 196 + i * 14 + j] > 0.f)
                           ? (ei + ejG[(size_t)b * 14 + j]) : -1.0e30f;
            e[j] = ev; mx = fmaxf(mx, ev);
        }
        float sum = 0.f;
        #pragma unroll
        for (int j = 0; j < 14; ++j) { float pp = __expf(e[j] - mx); e[j] = pp; sum += pp; }
        float inv = 1.0f / sum;
        #pragma unroll
        for (int j = 0; j < 14; ++j) s_attn[i * 14 + j] = e[j] * inv;
    }
    __syncthreads();

    if (tid < 196) attn_out[(size_t)b * 196 + tid] = s_attn[tid];

    for (int pp = tid; pp < 14 * 48; pp += 256) {
        const int i  = pp / 48;
        const int d0 = (pp % 48) * 16;
        float acc[16];
        #pragma unroll
        for (int qq = 0; qq < 16; ++qq) acc[qq] = b_out[d0 + qq];
        #pragma unroll
        for (int j = 0; j < 14; ++j) {
            float aw = s_attn[i * 14 + j];
            u16x8 wv0 = *(const u16x8*)&wh[j * 768 + d0];
            u16x8 wv1 = *(const u16x8*)&wh[j * 768 + d0 + 8];
            #pragma unroll
            for (int qq = 0; qq < 8; ++qq) {
                acc[qq]     += aw * bf2f(wv0[qq]);
                acc[8 + qq] += aw * bf2f(wv1[qq]);
            }
        }
        float* dst = &outp[(size_t)b * 10752 + i * 768 + d0];
        *(float4*)(dst)      = *(float4*)&acc[0];
        *(float4*)(dst + 4)  = *(float4*)&acc[4];
        *(float4*)(dst + 8)  = *(float4*)&acc[8];
        *(float4*)(dst + 12) = *(float4*)&acc[12];
    }
}

extern "C" void kernel_launch(void* const* d_in, const int* in_sizes, int n_in,
                              void* d_out, int out_size, void* d_ws, size_t ws_size,
                              hipStream_t stream)
{
    const float* features = (const float*)d_in[0];
    const float* adj      = (const float*)d_in[1];
    const float* W_emb    = (const float*)d_in[2];
    const float* b_emb    = (const float*)d_in[3];
    const float* gat_W    = (const float*)d_in[4];
    const float* gat_a    = (const float*)d_in[5];
    const float* W_out    = (const float*)d_in[6];
    const float* b_out    = (const float*)d_in[7];
    float* out = (float*)d_out;

    // ws: Wh (bf16 57344x768) | Wt[7] | scr f32 1536x768 | vecs | ei/ej
    u16* Wh = (u16*)d_ws;
    u16* Wt = Wh + 44040192;
    float* scr  = (float*)(Wt + 7 * 589824);
    float* w3ai = scr + 1179648;
    float* w3aj = w3ai + 768;
    float* bfus = w3aj + 768;
    float* eiG  = bfus + 768;
    float* ejG  = eiG + 57344;
    // out-region: ping-pong bf16 halves; WeW3 staging aliases H0 (dead by mix0)
    u16* H0 = (u16*)d_out;
    u16* H1 = H0 + 44040192;
    u16* WeW3 = H0;
    float* attn0 = out + 44040192;
    float* attn1 = attn0 + 802816;
    float* attn2 = attn1 + 802816;

    // ---- prep ----
    conv_w<<<dim3(720), 256, 0, stream>>>(W_emb, gat_W, W_out, Wt);
    conv_x<<<dim3(576), 256, 0, stream>>>((const float4*)W_emb, WeW3, 147456);
    conv_x<<<dim3(576), 256, 0, stream>>>((const float4*)(gat_W + 2 * 589824), WeW3 + 589824, 147456);
    prep_vecs<<<dim3(3), 256, 0, stream>>>(gat_W + 2 * 589824, gat_a + 2 * 1536, b_emb,
                                           Wt + 589824, w3ai, w3aj, bfus);
    // stacked prep GEMM: [We;W3] @ {W1t | W_out_t} -> scr (1536x768 fp32)
    gemm_bt<true, false, false><<<dim3(72), 256, 0, stream>>>(
        WeW3, Wt + 1 * 589824, Wt + 4 * 589824, nullptr, scr);
    conv_w2<<<dim3(288), 256, 0, stream>>>(scr, Wt + 5 * 589824);

    dim3 gg(2688);
    // layer 0 (embed fused, fp32 A): Wh1 = features @ (We*W1) + be*W1
    gemm_bt<false, true, true><<<gg, 256, 0, stream>>>(
        features, Wt + 5 * 589824, nullptr, bfus, Wh);
    gat_mix<true, false><<<dim3(4096), 256, 0, stream>>>(Wh, adj, gat_a, attn0, H0,
                                                         nullptr, nullptr, nullptr, nullptr);
    // layer 1: Wh2 = x1 @ W2 ; mix also emits ei3/ej3
    gemm_bt<false, true, false><<<gg, 256, 0, stream>>>(
        H0, Wt + 2 * 589824, nullptr, nullptr, Wh);
    gat_mix<true, true><<<dim3(4096), 256, 0, stream>>>(Wh, adj, gat_a + 1536, attn1, H1,
                                                        w3ai, w3aj, eiG, ejG);
    // layer 2 + out-proj fused: Z = x2 @ (W3*W_out); out = attn2 @ Z + b_out
    gemm_bt<false, true, false><<<gg, 256, 0, stream>>>(
        H1, Wt + 6 * 589824, nullptr, nullptr, Wh);
    gat_out<<<dim3(4096), 256, 0, stream>>>(Wh, adj, eiG, ejG, b_out, attn2, out);
}

// Round 12
// 651.927 us; speedup vs baseline: 1.1424x; 1.0122x over previous
//
#include <hip/hip_runtime.h>

typedef unsigned short u16;
typedef float f32x16 __attribute__((ext_vector_type(16)));
typedef short bf16x8 __attribute__((ext_vector_type(8)));
typedef unsigned short u16x8 __attribute__((ext_vector_type(8)));

#define ND 768
#define KD 768

__device__ __forceinline__ float bf2f(u16 u) {
    union { unsigned i; float f; } v; v.i = ((unsigned)u) << 16; return v.f;
}
__device__ __forceinline__ u16 f2bf(float f) {
    union { float f; unsigned u; } x; x.f = f;
    unsigned r = x.u + 0x7fffu + ((x.u >> 16) & 1u);
    return (u16)(r >> 16);
}
__device__ __forceinline__ void async16(const void* g, void* l) {
    __builtin_amdgcn_global_load_lds((const __attribute__((address_space(1))) void*)g,
                                     (__attribute__((address_space(3))) void*)l, 16, 0, 0);
}

// ---- transpose+convert 5 weights via LDS tiles: Wt[m][n][k] = bf16(W_m[k][n]) ----
__global__ __launch_bounds__(256) void conv_w(const float* __restrict__ W_emb,
                                              const float* __restrict__ gat_W,
                                              const float* __restrict__ W_out,
                                              u16* __restrict__ Wt)
{
    __shared__ float lds[64][65];
    const int m  = blockIdx.x / 144;
    const int r  = blockIdx.x % 144;
    const int tr = r / 12;
    const int tc = r % 12;
    const float* src = (m == 0) ? W_emb : (m <= 3) ? (gat_W + (size_t)(m - 1) * 589824) : W_out;
    const int c  = threadIdx.x & 63;
    const int w4 = threadIdx.x >> 6;
    #pragma unroll
    for (int i = 0; i < 16; ++i) {
        int kk = i * 4 + w4;
        lds[kk][c] = src[(size_t)(tr * 64 + kk) * 768 + tc * 64 + c];
    }
    __syncthreads();
    u16* dst = Wt + (size_t)m * 589824;
    #pragma unroll
    for (int i = 0; i < 16; ++i) {
        int nn = i * 4 + w4;
        dst[(size_t)(tc * 64 + nn) * 768 + tr * 64 + c] = f2bf(lds[c][nn]);
    }
}

// ---- transpose both halves of scr (1536x768 fp32) into Wt5, Wt6 (bf16 K-major) ----
__global__ __launch_bounds__(256) void conv_w2(const float* __restrict__ src0,
                                               u16* __restrict__ dst0)
{
    __shared__ float lds[64][65];
    const int m  = blockIdx.x / 144;          // 0: We*W1, 1: W3*Wout
    const int r  = blockIdx.x % 144;
    const int tr = r / 12;
    const int tc = r % 12;
    const float* src = src0 + (size_t)m * 589824;
    u16* dst = dst0 + (size_t)m * 589824;
    const int c  = threadIdx.x & 63;
    const int w4 = threadIdx.x >> 6;
    #pragma unroll
    for (int i = 0; i < 16; ++i) {
        int kk = i * 4 + w4;
        lds[kk][c] = src[(size_t)(tr * 64 + kk) * 768 + tc * 64 + c];
    }
    __syncthreads();
    #pragma unroll
    for (int i = 0; i < 16; ++i) {
        int nn = i * 4 + w4;
        dst[(size_t)(tc * 64 + nn) * 768 + tr * 64 + c] = f2bf(lds[c][nn]);
    }
}

// ---- fp32 -> bf16 bulk convert ----
__global__ __launch_bounds__(256) void conv_x(const float4* __restrict__ in,
                                              u16* __restrict__ outp, int n4)
{
    for (int i = blockIdx.x * 256 + threadIdx.x; i < n4; i += gridDim.x * 256) {
        float4 v = in[i];
        union { u16 s[4]; uint2 u; } o;
        o.s[0] = f2bf(v.x); o.s[1] = f2bf(v.y); o.s[2] = f2bf(v.z); o.s[3] = f2bf(v.w);
        ((uint2*)outp)[i] = o.u;
    }
}

// ---- tiny precompute: w3ai[k]=W3[k]:·a_i, w3aj[k]=W3[k]:·a_j, bfus[n]=be·W1[:,n] ----
__global__ __launch_bounds__(256) void prep_vecs(const float* __restrict__ W3,
                                                 const float* __restrict__ ga2,
                                                 const float* __restrict__ be,
                                                 const u16* __restrict__ Wt1,
                                                 float* __restrict__ w3ai,
                                                 float* __restrict__ w3aj,
                                                 float* __restrict__ bfus)
{
    int d = blockIdx.x * 256 + threadIdx.x;
    if (d >= 768) return;
    const float* row = W3 + (size_t)d * 768;
    float ai = 0.f, aj = 0.f;
    for (int n = 0; n < 768; ++n) { float w = row[n]; ai += w * ga2[n]; aj += w * ga2[768 + n]; }
    w3ai[d] = ai; w3aj[d] = aj;
    const u16* wt = Wt1 + (size_t)d * 768;
    float bf = 0.f;
    for (int j = 0; j < 768; ++j) bf += be[j] * bf2f(wt[j]);
    bfus[d] = bf;
}

// ---- bf16 GEMM, single-barrier double-buffered prefetch + 32x32x16 MFMA ----
// Loop rotation makes the post-MFMA barrier redundant: STAGE(t+1 -> buf^)
// is issued AFTER the top-of-iter __syncthreads(), which guarantees all
// waves' ds_reads of buf^ (iter t-1) completed (compiler lgkmcnt precedes
// their MFMAs). __syncthreads also drains vmcnt(0) = buf[cur] staged one
// full compute phase ago. One barrier per K-step, zero inline asm.
// Bt2: optional second B selected when tm>=768 (stacked prep GEMM).
template<bool F32OUT, bool SWZ>
__global__ __launch_bounds__(256) void gemm_bt(const u16* __restrict__ A,
                                               const u16* __restrict__ Bt,
                                               const u16* __restrict__ Bt2,
                                               const float* __restrict__ bias,
                                               void* __restrict__ Cout)
{
    __shared__ u16 lds2[2][2][4096];
    const int tid  = threadIdx.x;
    const int lane = tid & 63;
    const int wvb  = tid & ~63;
    const int wm   = ((tid >> 7) & 1) * 64;
    const int wn   = ((tid >> 6) & 1) * 64;
    const int wg = blockIdx.x;
    const int id = SWZ ? ((wg & 7) * 336 + (wg >> 3)) : wg;
    const int tn = (id % 6) * 128;
    const int tm = (id / 6) * 128;
    const u16* BtU = (Bt2 != nullptr && tm >= 768) ? Bt2 : Bt;

    f32x16 acc[2][2] = {};

    const int r31 = lane & 31;
    const int l5  = lane >> 5;
    const int key = (r31 >> 1) & 3;

    const int row0 = tid >> 2;
    const int kc0  = (((tid & 3) ^ ((tid >> 3) & 3)) << 3);
    const u16* aSrc = A   + (size_t)(tm + row0) * KD + kc0;
    const u16* bSrc = BtU + (size_t)(tn + row0) * KD + kc0;

    #define STAGE(b, ks_) { const int k0 = (ks_) * 32;                      \
        async16(aSrc + k0,                  &lds2[b][0][wvb * 8]);          \
        async16(aSrc + (size_t)64 * KD + k0, &lds2[b][0][(256 + wvb) * 8]); \
        async16(bSrc + k0,                  &lds2[b][1][wvb * 8]);          \
        async16(bSrc + (size_t)64 * KD + k0, &lds2[b][1][(256 + wvb) * 8]); }

    STAGE(0, 0);

    #pragma unroll 2
    for (int ks = 0; ks < KD / 32; ++ks) {
        const int cur = ks & 1;
        __syncthreads();                    // drain vmcnt(0) + join (buf[cur] ready;
                                            // all reads of buf[cur^1] finished)
        if (ks + 1 < KD / 32) STAGE(cur ^ 1, ks + 1);   // prefetch next tile

        const u16* As = lds2[cur][0];
        const u16* Bs = lds2[cur][1];
        bf16x8 af[2][2], bf[2][2];
        #pragma unroll
        for (int fr = 0; fr < 2; ++fr)
            #pragma unroll
            for (int ka = 0; ka < 2; ++ka) {
                int chA = ((ka * 2 + l5) ^ key) << 3;
                af[fr][ka] = *(const bf16x8*)&As[(wm + fr * 32 + r31) * 32 + chA];
                bf[fr][ka] = *(const bf16x8*)&Bs[(wn + fr * 32 + r31) * 32 + chA];
            }
        #pragma unroll
        for (int fr = 0; fr < 2; ++fr)
            #pragma unroll
            for (int fc = 0; fc < 2; ++fc)
                #pragma unroll
                for (int ka = 0; ka < 2; ++ka)
                    acc[fr][fc] = __builtin_amdgcn_mfma_f32_32x32x16_bf16(
                        af[fr][ka], bf[fc][ka], acc[fr][fc], 0, 0, 0);
    }
    #undef STAGE

    // epilogue: 32x32 C/D layout col=lane&31, row=(reg&3)+8*(reg>>2)+4*(lane>>5)
    #pragma unroll
    for (int fc = 0; fc < 2; ++fc) {
        int col = tn + wn + fc * 32 + r31;
        float bv = bias ? bias[col] : 0.0f;
        #pragma unroll
        for (int fr = 0; fr < 2; ++fr) {
            int rowb = tm + wm + fr * 32 + 4 * l5;
            #pragma unroll
            for (int reg = 0; reg < 16; ++reg) {
                int row = rowb + (reg & 3) + 8 * (reg >> 2);
                float v = acc[fr][fc][reg] + bv;
                if (F32OUT)
                    ((float*)Cout)[(size_t)row * ND + col] = v;
                else
                    ((u16*)Cout)[(size_t)row * ND + col] = f2bf(v);
            }
        }
    }
}

// ---- fused GAT attention: ei/ej from staged Wh, softmax, mix, ELU ----
template<bool ELU, bool DOTS>
__global__ __launch_bounds__(256) void gat_mix(const u16* __restrict__ Wh,
                                               const float* __restrict__ adj,
                                               const float* __restrict__ avec,
                                               float* __restrict__ attn_out,
                                               u16* __restrict__ Xout,
                                               const float* __restrict__ w3ai,
                                               const float* __restrict__ w3aj,
                                               float* __restrict__ eiOut,
                                               float* __restrict__ ejOut)
{
    __shared__ u16 wh[14 * 768];
    __shared__ float s_ei[14], s_ej[14];
    __shared__ float s_attn[196];
    __shared__ float s_dots[14][2];
    const int b = blockIdx.x;
    const int tid = threadIdx.x;
    const u16* whb = Wh + (size_t)b * 10752;

    if (DOTS && tid < 28) ((float*)s_dots)[tid] = 0.f;
    for (int c = tid; c < 1344; c += 256)
        ((uint4*)wh)[c] = ((const uint4*)whb)[c];
    __syncthreads();

    if (tid < 224) {
        const int i = tid >> 4, l = tid & 15;
        float ai = 0.f, aj = 0.f;
        #pragma unroll
        for (int c = 0; c < 6; ++c) {
            int d = c * 128 + l * 8;
            u16x8 v  = *(const u16x8*)&wh[i * 768 + d];
            float4 x0 = *(const float4*)&avec[d];
            float4 x1 = *(const float4*)&avec[d + 4];
            float4 y0 = *(const float4*)&avec[768 + d];
            float4 y1 = *(const float4*)&avec[768 + d + 4];
            float w0 = bf2f(v[0]), w1 = bf2f(v[1]), w2 = bf2f(v[2]), w3 = bf2f(v[3]);
            float w4 = bf2f(v[4]), w5 = bf2f(v[5]), w6 = bf2f(v[6]), w7 = bf2f(v[7]);
            ai += w0*x0.x + w1*x0.y + w2*x0.z + w3*x0.w + w4*x1.x + w5*x1.y + w6*x1.z + w7*x1.w;
            aj += w0*y0.x + w1*y0.y + w2*y0.z + w3*y0.w + w4*y1.x + w5*y1.y + w6*y1.z + w7*y1.w;
        }
        #pragma unroll
        for (int off = 8; off; off >>= 1) {
            ai += __shfl_xor(ai, off);
            aj += __shfl_xor(aj, off);
        }
        if (l == 0) { s_ei[i] = ai; s_ej[i] = aj; }
    }
    __syncthreads();

    if (tid < 14) {
        const int i = tid;
        float e[14];
        float mx = -3.0e38f;
        #pragma unroll
        for (int j = 0; j < 14; ++j) {
            float ev = (adj[(size_t)b * 196 + i * 14 + j] > 0.f) ? (s_ei[i] + s_ej[j]) : -1.0e30f;
            e[j] = ev; mx = fmaxf(mx, ev);
        }
        float sum = 0.f;
        #pragma unroll
        for (int j = 0; j < 14; ++j) { float pp = __expf(e[j] - mx); e[j] = pp; sum += pp; }
        float inv = 1.0f / sum;
        #pragma unroll
        for (int j = 0; j < 14; ++j) s_attn[i * 14 + j] = e[j] * inv;
    }
    __syncthreads();

    if (tid < 196) attn_out[(size_t)b * 196 + tid] = s_attn[tid];

    for (int pp = tid; pp < 14 * 48; pp += 256) {
        const int i  = pp / 48;
        const int d0 = (pp % 48) * 16;
        float acc[16] = {};
        #pragma unroll
        for (int j = 0; j < 14; ++j) {
            float aw = s_attn[i * 14 + j];
            u16x8 wv0 = *(const u16x8*)&wh[j * 768 + d0];
            u16x8 wv1 = *(const u16x8*)&wh[j * 768 + d0 + 8];
            #pragma unroll
            for (int qq = 0; qq < 8; ++qq) {
                acc[qq]     += aw * bf2f(wv0[qq]);
                acc[8 + qq] += aw * bf2f(wv1[qq]);
            }
        }
        float pi = 0.f, pj = 0.f;
        union { u16 s[16]; uint4 u[2]; } o;
        #pragma unroll
        for (int qq = 0; qq < 16; ++qq) {
            float v = acc[qq];
            if (ELU && v < 0.f) v = __expf(v) - 1.0f;
            if (DOTS) { pi += v * w3ai[d0 + qq]; pj += v * w3aj[d0 + qq]; }
            o.s[qq] = f2bf(v);
        }
        if (DOTS) {
            atomicAdd(&s_dots[i][0], pi);
            atomicAdd(&s_dots[i][1], pj);
        }
        *(uint4*)&Xout[(size_t)b * 10752 + i * 768 + d0]     = o.u[0];
        *(uint4*)&Xout[(size_t)b * 10752 + i * 768 + d0 + 8] = o.u[1];
    }
    if (DOTS) {
        __syncthreads();
        if (tid < 14) {
            eiOut[(size_t)b * 14 + tid] = s_dots[tid][0];
            ejOut[(size_t)b * 14 + tid] = s_dots[tid][1];
        }
    }
}

// ---- final layer: softmax from precomputed ei3/ej3, out = attn2 @ Z + b_out ----
__global__ __launch_bounds__(256) void gat_out(const u16* __restrict__ Z,
                                               const float* __restrict__ adj,
                                               const float* __restrict__ eiG,
                                               const float* __restrict__ ejG,
                                               const float* __restrict__ b_out,
                                               float* __restrict__ attn_out,
                                               float* __restrict__ outp)
{
    __shared__ u16 wh[14 * 768];
    __shared__ float s_attn[196];
    const int b = blockIdx.x;
    const int tid = threadIdx.x;
    const u16* zb = Z + (size_t)b * 10752;

    for (int c = tid; c < 1344; c += 256)
        ((uint4*)wh)[c] = ((const uint4*)zb)[c];

    if (tid < 14) {
        const int i = tid;
        float ei = eiG[(size_t)b * 14 + i];
        float e[14];
        float mx = -3.0e38f;
        #pragma unroll
        for (int j = 0; j < 14; ++j) {
            float ev = (adj[(size_t)b * 196 + i * 14 + j] > 0.f)
                           ? (ei + ejG[(size_t)b * 14 + j]) : -1.0e30f;
            e[j] = ev; mx = fmaxf(mx, ev);
        }
        float sum = 0.f;
        #pragma unroll
        for (int j = 0; j < 14; ++j) { float pp = __expf(e[j] - mx); e[j] = pp; sum += pp; }
        float inv = 1.0f / sum;
        #pragma unroll
        for (int j = 0; j < 14; ++j) s_attn[i * 14 + j] = e[j] * inv;
    }
    __syncthreads();

    if (tid < 196) attn_out[(size_t)b * 196 + tid] = s_attn[tid];

    for (int pp = tid; pp < 14 * 48; pp += 256) {
        const int i  = pp / 48;
        const int d0 = (pp % 48) * 16;
        float acc[16];
        #pragma unroll
        for (int qq = 0; qq < 16; ++qq) acc[qq] = b_out[d0 + qq];
        #pragma unroll
        for (int j = 0; j < 14; ++j) {
            float aw = s_attn[i * 14 + j];
            u16x8 wv0 = *(const u16x8*)&wh[j * 768 + d0];
            u16x8 wv1 = *(const u16x8*)&wh[j * 768 + d0 + 8];
            #pragma unroll
            for (int qq = 0; qq < 8; ++qq) {
                acc[qq]     += aw * bf2f(wv0[qq]);
                acc[8 + qq] += aw * bf2f(wv1[qq]);
            }
        }
        float* dst = &outp[(size_t)b * 10752 + i * 768 + d0];
        *(float4*)(dst)      = *(float4*)&acc[0];
        *(float4*)(dst + 4)  = *(float4*)&acc[4];
        *(float4*)(dst + 8)  = *(float4*)&acc[8];
        *(float4*)(dst + 12) = *(float4*)&acc[12];
    }
}

extern "C" void kernel_launch(void* const* d_in, const int* in_sizes, int n_in,
                              void* d_out, int out_size, void* d_ws, size_t ws_size,
                              hipStream_t stream)
{
    const float* features = (const float*)d_in[0];
    const float* adj      = (const float*)d_in[1];
    const float* W_emb    = (const float*)d_in[2];
    const float* b_emb    = (const float*)d_in[3];
    const float* gat_W    = (const float*)d_in[4];
    const float* gat_a    = (const float*)d_in[5];
    const float* W_out    = (const float*)d_in[6];
    const float* b_out    = (const float*)d_in[7];
    float* out = (float*)d_out;

    // ws: Wh (bf16 57344x768) | Wt[7] | scr f32 1536x768 | vecs | ei/ej
    u16* Wh = (u16*)d_ws;
    u16* Wt = Wh + 44040192;
    float* scr  = (float*)(Wt + 7 * 589824);
    float* w3ai = scr + 1179648;
    float* w3aj = w3ai + 768;
    float* bfus = w3aj + 768;
    float* eiG  = bfus + 768;
    float* ejG  = eiG + 57344;
    // out-region: ping-pong bf16 halves; WeW3 staging aliases H1 (dead by mix0)
    u16* H0 = (u16*)d_out;
    u16* H1 = H0 + 44040192;
    u16* WeW3 = H1;
    float* attn0 = out + 44040192;
    float* attn1 = attn0 + 802816;
    float* attn2 = attn1 + 802816;

    // ---- prep ----
    conv_w<<<dim3(720), 256, 0, stream>>>(W_emb, gat_W, W_out, Wt);
    conv_x<<<dim3(4096), 256, 0, stream>>>((const float4*)features, H0, 11010048);
    conv_x<<<dim3(576), 256, 0, stream>>>((const float4*)W_emb, WeW3, 147456);
    conv_x<<<dim3(576), 256, 0, stream>>>((const float4*)(gat_W + 2 * 589824), WeW3 + 589824, 147456);
    prep_vecs<<<dim3(3), 256, 0, stream>>>(gat_W + 2 * 589824, gat_a + 2 * 1536, b_emb,
                                           Wt + 589824, w3ai, w3aj, bfus);
    // stacked prep GEMM: [We;W3] @ {W1t | W_out_t} -> scr (1536x768 fp32)
    gemm_bt<true, false><<<dim3(72), 256, 0, stream>>>(
        WeW3, Wt + 1 * 589824, Wt + 4 * 589824, nullptr, scr);
    conv_w2<<<dim3(288), 256, 0, stream>>>(scr, Wt + 5 * 589824);

    dim3 gg(2688);
    // layer 0 (embed fused): Wh1 = features_bf16 @ (We*W1) + be*W1
    gemm_bt<false, true><<<gg, 256, 0, stream>>>(
        H0, Wt + 5 * 589824, nullptr, bfus, Wh);
    gat_mix<true, false><<<dim3(4096), 256, 0, stream>>>(Wh, adj, gat_a, attn0, H1,
                                                         nullptr, nullptr, nullptr, nullptr);
    // layer 1: Wh2 = x1 @ W2 ; mix also emits ei3/ej3
    gemm_bt<false, true><<<gg, 256, 0, stream>>>(
        H1, Wt + 2 * 589824, nullptr, nullptr, Wh);
    gat_mix<true, true><<<dim3(4096), 256, 0, stream>>>(Wh, adj, gat_a + 1536, attn1, H0,
                                                        w3ai, w3aj, eiG, ejG);
    // layer 2 + out-proj fused: Z = x2 @ (W3*W_out); out = attn2 @ Z + b_out
    gemm_bt<false, true><<<gg, 256, 0, stream>>>(
        H0, Wt + 6 * 589824, nullptr, nullptr, Wh);
    gat_out<<<dim3(4096), 256, 0, stream>>>(Wh, adj, eiG, ejG, b_out, attn2, out);
}

// Round 13
// 638.624 us; speedup vs baseline: 1.1662x; 1.0208x over previous
//
#include <hip/hip_runtime.h>

typedef unsigned short u16;
typedef float f32x16 __attribute__((ext_vector_type(16)));
typedef short bf16x8 __attribute__((ext_vector_type(8)));
typedef unsigned short u16x8 __attribute__((ext_vector_type(8)));

#define ND 768
#define KD 768

__device__ __forceinline__ float bf2f(u16 u) {
    union { unsigned i; float f; } v; v.i = ((unsigned)u) << 16; return v.f;
}
__device__ __forceinline__ u16 f2bf(float f) {
    union { float f; unsigned u; } x; x.f = f;
    unsigned r = x.u + 0x7fffu + ((x.u >> 16) & 1u);
    return (u16)(r >> 16);
}
__device__ __forceinline__ void async16(const void* g, void* l) {
    __builtin_amdgcn_global_load_lds((const __attribute__((address_space(1))) void*)g,
                                     (__attribute__((address_space(3))) void*)l, 16, 0, 0);
}

// ---- transpose+convert 5 weights via LDS tiles: Wt[m][n][k] = bf16(W_m[k][n]) ----
__global__ __launch_bounds__(256) void conv_w(const float* __restrict__ W_emb,
                                              const float* __restrict__ gat_W,
                                              const float* __restrict__ W_out,
                                              u16* __restrict__ Wt)
{
    __shared__ float lds[64][65];
    const int m  = blockIdx.x / 144;
    const int r  = blockIdx.x % 144;
    const int tr = r / 12;
    const int tc = r % 12;
    const float* src = (m == 0) ? W_emb : (m <= 3) ? (gat_W + (size_t)(m - 1) * 589824) : W_out;
    const int c  = threadIdx.x & 63;
    const int w4 = threadIdx.x >> 6;
    #pragma unroll
    for (int i = 0; i < 16; ++i) {
        int kk = i * 4 + w4;
        lds[kk][c] = src[(size_t)(tr * 64 + kk) * 768 + tc * 64 + c];
    }
    __syncthreads();
    u16* dst = Wt + (size_t)m * 589824;
    #pragma unroll
    for (int i = 0; i < 16; ++i) {
        int nn = i * 4 + w4;
        dst[(size_t)(tc * 64 + nn) * 768 + tr * 64 + c] = f2bf(lds[c][nn]);
    }
}

// ---- transpose both halves of scr (1536x768 fp32) into Wt5, Wt6 (bf16 K-major) ----
__global__ __launch_bounds__(256) void conv_w2(const float* __restrict__ src0,
                                               u16* __restrict__ dst0)
{
    __shared__ float lds[64][65];
    const int m  = blockIdx.x / 144;          // 0: We*W1, 1: W3*Wout
    const int r  = blockIdx.x % 144;
    const int tr = r / 12;
    const int tc = r % 12;
    const float* src = src0 + (size_t)m * 589824;
    u16* dst = dst0 + (size_t)m * 589824;
    const int c  = threadIdx.x & 63;
    const int w4 = threadIdx.x >> 6;
    #pragma unroll
    for (int i = 0; i < 16; ++i) {
        int kk = i * 4 + w4;
        lds[kk][c] = src[(size_t)(tr * 64 + kk) * 768 + tc * 64 + c];
    }
    __syncthreads();
    #pragma unroll
    for (int i = 0; i < 16; ++i) {
        int nn = i * 4 + w4;
        dst[(size_t)(tc * 64 + nn) * 768 + tr * 64 + c] = f2bf(lds[c][nn]);
    }
}

// ---- fp32 -> bf16 bulk convert ----
__global__ __launch_bounds__(256) void conv_x(const float4* __restrict__ in,
                                              u16* __restrict__ outp, int n4)
{
    for (int i = blockIdx.x * 256 + threadIdx.x; i < n4; i += gridDim.x * 256) {
        float4 v = in[i];
        union { u16 s[4]; uint2 u; } o;
        o.s[0] = f2bf(v.x); o.s[1] = f2bf(v.y); o.s[2] = f2bf(v.z); o.s[3] = f2bf(v.w);
        ((uint2*)outp)[i] = o.u;
    }
}

// ---- tiny precompute: w3ai[k]=W3[k]:·a_i, w3aj[k]=W3[k]:·a_j, bfus[n]=be·W1[:,n] ----
__global__ __launch_bounds__(256) void prep_vecs(const float* __restrict__ W3,
                                                 const float* __restrict__ ga2,
                                                 const float* __restrict__ be,
                                                 const u16* __restrict__ Wt1,
                                                 float* __restrict__ w3ai,
                                                 float* __restrict__ w3aj,
                                                 float* __restrict__ bfus)
{
    int d = blockIdx.x * 256 + threadIdx.x;
    if (d >= 768) return;
    const float* row = W3 + (size_t)d * 768;
    float ai = 0.f, aj = 0.f;
    for (int n = 0; n < 768; ++n) { float w = row[n]; ai += w * ga2[n]; aj += w * ga2[768 + n]; }
    w3ai[d] = ai; w3aj[d] = aj;
    const u16* wt = Wt1 + (size_t)d * 768;
    float bf = 0.f;
    for (int j = 0; j < 768; ++j) bf += be[j] * bf2f(wt[j]);
    bfus[d] = bf;
}

// ---- bf16 GEMM: depth-2 prefetch, 3-buffer circular LDS, counted vmcnt(4) ----
// Loop: {vmcnt(4) [drain oldest stage-group only] -> s_barrier -> STAGE(t+2)
// -> compute(t)}. Each buffer's loads get TWO K-steps of flight (HBM latency
// cover). Single barrier per step: STAGE(t+2) after barrier(t) is safe since
// all waves finished compute(t-1) (last reader of that buffer). Per-wave
// vmcnt -> barrier ordering = R7-verified pattern. T2 XOR swizzle kept.
// Bt2: optional second B selected when tm>=768 (stacked prep GEMM).
template<bool F32OUT, bool SWZ>
__global__ __launch_bounds__(256) void gemm_bt(const u16* __restrict__ A,
                                               const u16* __restrict__ Bt,
                                               const u16* __restrict__ Bt2,
                                               const float* __restrict__ bias,
                                               void* __restrict__ Cout)
{
    __shared__ u16 lds3[3][2][4096];   // 48 KB: 3 slots x (A | B) x 128r x 32
    const int tid  = threadIdx.x;
    const int lane = tid & 63;
    const int wvb  = tid & ~63;
    const int wm   = ((tid >> 7) & 1) * 64;
    const int wn   = ((tid >> 6) & 1) * 64;
    const int wg = blockIdx.x;
    const int id = SWZ ? ((wg & 7) * 336 + (wg >> 3)) : wg;
    const int tn = (id % 6) * 128;
    const int tm = (id / 6) * 128;
    const u16* BtU = (Bt2 != nullptr && tm >= 768) ? Bt2 : Bt;

    f32x16 acc[2][2] = {};

    const int r31 = lane & 31;
    const int l5  = lane >> 5;
    const int key = (r31 >> 1) & 3;

    const int row0 = tid >> 2;
    const int kc0  = (((tid & 3) ^ ((tid >> 3) & 3)) << 3);
    const u16* aSrc = A   + (size_t)(tm + row0) * KD + kc0;
    const u16* bSrc = BtU + (size_t)(tn + row0) * KD + kc0;

    #define STAGE(b, ks_) { const int k0 = (ks_) * 32;                       \
        async16(aSrc + k0,                   &lds3[b][0][wvb * 8]);          \
        async16(aSrc + (size_t)64 * KD + k0, &lds3[b][0][(256 + wvb) * 8]);  \
        async16(bSrc + k0,                   &lds3[b][1][wvb * 8]);          \
        async16(bSrc + (size_t)64 * KD + k0, &lds3[b][1][(256 + wvb) * 8]); }

    STAGE(0, 0);
    STAGE(1, 1);

    #pragma unroll 3
    for (int ks = 0; ks < KD / 32; ++ks) {
        const int cur = ks % 3;
        if (ks < KD / 32 - 1)
            asm volatile("s_waitcnt vmcnt(4)" ::: "memory");  // drain group ks only
        else
            asm volatile("s_waitcnt vmcnt(0)" ::: "memory");  // tail
        __builtin_amdgcn_s_barrier();
        asm volatile("" ::: "memory");
        if (ks + 2 < KD / 32) STAGE((ks + 2) % 3, ks + 2);    // depth-2 prefetch

        const u16* As = lds3[cur][0];
        const u16* Bs = lds3[cur][1];
        bf16x8 af[2][2], bf[2][2];
        #pragma unroll
        for (int fr = 0; fr < 2; ++fr)
            #pragma unroll
            for (int ka = 0; ka < 2; ++ka) {
                int chA = ((ka * 2 + l5) ^ key) << 3;
                af[fr][ka] = *(const bf16x8*)&As[(wm + fr * 32 + r31) * 32 + chA];
                bf[fr][ka] = *(const bf16x8*)&Bs[(wn + fr * 32 + r31) * 32 + chA];
            }
        #pragma unroll
        for (int fr = 0; fr < 2; ++fr)
            #pragma unroll
            for (int fc = 0; fc < 2; ++fc)
                #pragma unroll
                for (int ka = 0; ka < 2; ++ka)
                    acc[fr][fc] = __builtin_amdgcn_mfma_f32_32x32x16_bf16(
                        af[fr][ka], bf[fc][ka], acc[fr][fc], 0, 0, 0);
    }
    #undef STAGE

    // epilogue: 32x32 C/D layout col=lane&31, row=(reg&3)+8*(reg>>2)+4*(lane>>5)
    #pragma unroll
    for (int fc = 0; fc < 2; ++fc) {
        int col = tn + wn + fc * 32 + r31;
        float bv = bias ? bias[col] : 0.0f;
        #pragma unroll
        for (int fr = 0; fr < 2; ++fr) {
            int rowb = tm + wm + fr * 32 + 4 * l5;
            #pragma unroll
            for (int reg = 0; reg < 16; ++reg) {
                int row = rowb + (reg & 3) + 8 * (reg >> 2);
                float v = acc[fr][fc][reg] + bv;
                if (F32OUT)
                    ((float*)Cout)[(size_t)row * ND + col] = v;
                else
                    ((u16*)Cout)[(size_t)row * ND + col] = f2bf(v);
            }
        }
    }
}

// ---- fused GAT attention: ei/ej from staged Wh, softmax, mix, ELU ----
template<bool ELU, bool DOTS>
__global__ __launch_bounds__(256) void gat_mix(const u16* __restrict__ Wh,
                                               const float* __restrict__ adj,
                                               const float* __restrict__ avec,
                                               float* __restrict__ attn_out,
                                               u16* __restrict__ Xout,
                                               const float* __restrict__ w3ai,
                                               const float* __restrict__ w3aj,
                                               float* __restrict__ eiOut,
                                               float* __restrict__ ejOut)
{
    __shared__ u16 wh[14 * 768];
    __shared__ float s_ei[14], s_ej[14];
    __shared__ float s_attn[196];
    __shared__ float s_dots[14][2];
    const int b = blockIdx.x;
    const int tid = threadIdx.x;
    const u16* whb = Wh + (size_t)b * 10752;

    if (DOTS && tid < 28) ((float*)s_dots)[tid] = 0.f;
    for (int c = tid; c < 1344; c += 256)
        ((uint4*)wh)[c] = ((const uint4*)whb)[c];
    __syncthreads();

    if (tid < 224) {
        const int i = tid >> 4, l = tid & 15;
        float ai = 0.f, aj = 0.f;
        #pragma unroll
        for (int c = 0; c < 6; ++c) {
            int d = c * 128 + l * 8;
            u16x8 v  = *(const u16x8*)&wh[i * 768 + d];
            float4 x0 = *(const float4*)&avec[d];
            float4 x1 = *(const float4*)&avec[d + 4];
            float4 y0 = *(const float4*)&avec[768 + d];
            float4 y1 = *(const float4*)&avec[768 + d + 4];
            float w0 = bf2f(v[0]), w1 = bf2f(v[1]), w2 = bf2f(v[2]), w3 = bf2f(v[3]);
            float w4 = bf2f(v[4]), w5 = bf2f(v[5]), w6 = bf2f(v[6]), w7 = bf2f(v[7]);
            ai += w0*x0.x + w1*x0.y + w2*x0.z + w3*x0.w + w4*x1.x + w5*x1.y + w6*x1.z + w7*x1.w;
            aj += w0*y0.x + w1*y0.y + w2*y0.z + w3*y0.w + w4*y1.x + w5*y1.y + w6*y1.z + w7*y1.w;
        }
        #pragma unroll
        for (int off = 8; off; off >>= 1) {
            ai += __shfl_xor(ai, off);
            aj += __shfl_xor(aj, off);
        }
        if (l == 0) { s_ei[i] = ai; s_ej[i] = aj; }
    }
    __syncthreads();

    if (tid < 14) {
        const int i = tid;
        float e[14];
        float mx = -3.0e38f;
        #pragma unroll
        for (int j = 0; j < 14; ++j) {
            float ev = (adj[(size_t)b * 196 + i * 14 + j] > 0.f) ? (s_ei[i] + s_ej[j]) : -1.0e30f;
            e[j] = ev; mx = fmaxf(mx, ev);
        }
        float sum = 0.f;
        #pragma unroll
        for (int j = 0; j < 14; ++j) { float pp = __expf(e[j] - mx); e[j] = pp; sum += pp; }
        float inv = 1.0f / sum;
        #pragma unroll
        for (int j = 0; j < 14; ++j) s_attn[i * 14 + j] = e[j] * inv;
    }
    __syncthreads();

    if (tid < 196) attn_out[(size_t)b * 196 + tid] = s_attn[tid];

    for (int pp = tid; pp < 14 * 48; pp += 256) {
        const int i  = pp / 48;
        const int d0 = (pp % 48) * 16;
        float acc[16] = {};
        #pragma unroll
        for (int j = 0; j < 14; ++j) {
            float aw = s_attn[i * 14 + j];
            u16x8 wv0 = *(const u16x8*)&wh[j * 768 + d0];
            u16x8 wv1 = *(const u16x8*)&wh[j * 768 + d0 + 8];
            #pragma unroll
            for (int qq = 0; qq < 8; ++qq) {
                acc[qq]     += aw * bf2f(wv0[qq]);
                acc[8 + qq] += aw * bf2f(wv1[qq]);
            }
        }
        float pi = 0.f, pj = 0.f;
        union { u16 s[16]; uint4 u[2]; } o;
        #pragma unroll
        for (int qq = 0; qq < 16; ++qq) {
            float v = acc[qq];
            if (ELU && v < 0.f) v = __expf(v) - 1.0f;
            if (DOTS) { pi += v * w3ai[d0 + qq]; pj += v * w3aj[d0 + qq]; }
            o.s[qq] = f2bf(v);
        }
        if (DOTS) {
            atomicAdd(&s_dots[i][0], pi);
            atomicAdd(&s_dots[i][1], pj);
        }
        *(uint4*)&Xout[(size_t)b * 10752 + i * 768 + d0]     = o.u[0];
        *(uint4*)&Xout[(size_t)b * 10752 + i * 768 + d0 + 8] = o.u[1];
    }
    if (DOTS) {
        __syncthreads();
        if (tid < 14) {
            eiOut[(size_t)b * 14 + tid] = s_dots[tid][0];
            ejOut[(size_t)b * 14 + tid] = s_dots[tid][1];
        }
    }
}

// ---- final layer: softmax from precomputed ei3/ej3, out = attn2 @ Z + b_out ----
__global__ __launch_bounds__(256) void gat_out(const u16* __restrict__ Z,
                                               const float* __restrict__ adj,
                                               const float* __restrict__ eiG,
                                               const float* __restrict__ ejG,
                                               const float* __restrict__ b_out,
                                               float* __restrict__ attn_out,
                                               float* __restrict__ outp)
{
    __shared__ u16 wh[14 * 768];
    __shared__ float s_attn[196];
    const int b = blockIdx.x;
    const int tid = threadIdx.x;
    const u16* zb = Z + (size_t)b * 10752;

    for (int c = tid; c < 1344; c += 256)
        ((uint4*)wh)[c] = ((const uint4*)zb)[c];

    if (tid < 14) {
        const int i = tid;
        float ei = eiG[(size_t)b * 14 + i];
        float e[14];
        float mx = -3.0e38f;
        #pragma unroll
        for (int j = 0; j < 14; ++j) {
            float ev = (adj[(size_t)b * 196 + i * 14 + j] > 0.f)
                           ? (ei + ejG[(size_t)b * 14 + j]) : -1.0e30f;
            e[j] = ev; mx = fmaxf(mx, ev);
        }
        float sum = 0.f;
        #pragma unroll
        for (int j = 0; j < 14; ++j) { float pp = __expf(e[j] - mx); e[j] = pp; sum += pp; }
        float inv = 1.0f / sum;
        #pragma unroll
        for (int j = 0; j < 14; ++j) s_attn[i * 14 + j] = e[j] * inv;
    }
    __syncthreads();

    if (tid < 196) attn_out[(size_t)b * 196 + tid] = s_attn[tid];

    for (int pp = tid; pp < 14 * 48; pp += 256) {
        const int i  = pp / 48;
        const int d0 = (pp % 48) * 16;
        float acc[16];
        #pragma unroll
        for (int qq = 0; qq < 16; ++qq) acc[qq] = b_out[d0 + qq];
        #pragma unroll
        for (int j = 0; j < 14; ++j) {
            float aw = s_attn[i * 14 + j];
            u16x8 wv0 = *(const u16x8*)&wh[j * 768 + d0];
            u16x8 wv1 = *(const u16x8*)&wh[j * 768 + d0 + 8];
            #pragma unroll
            for (int qq = 0; qq < 8; ++qq) {
                acc[qq]     += aw * bf2f(wv0[qq]);
                acc[8 + qq] += aw * bf2f(wv1[qq]);
            }
        }
        float* dst = &outp[(size_t)b * 10752 + i * 768 + d0];
        *(float4*)(dst)      = *(float4*)&acc[0];
        *(float4*)(dst + 4)  = *(float4*)&acc[4];
        *(float4*)(dst + 8)  = *(float4*)&acc[8];
        *(float4*)(dst + 12) = *(float4*)&acc[12];
    }
}

extern "C" void kernel_launch(void* const* d_in, const int* in_sizes, int n_in,
                              void* d_out, int out_size, void* d_ws, size_t ws_size,
                              hipStream_t stream)
{
    const float* features = (const float*)d_in[0];
    const float* adj      = (const float*)d_in[1];
    const float* W_emb    = (const float*)d_in[2];
    const float* b_emb    = (const float*)d_in[3];
    const float* gat_W    = (const float*)d_in[4];
    const float* gat_a    = (const float*)d_in[5];
    const float* W_out    = (const float*)d_in[6];
    const float* b_out    = (const float*)d_in[7];
    float* out = (float*)d_out;

    // ws: Wh (bf16 57344x768) | Wt[7] | scr f32 1536x768 | vecs | ei/ej
    u16* Wh = (u16*)d_ws;
    u16* Wt = Wh + 44040192;
    float* scr  = (float*)(Wt + 7 * 589824);
    float* w3ai = scr + 1179648;
    float* w3aj = w3ai + 768;
    float* bfus = w3aj + 768;
    float* eiG  = bfus + 768;
    float* ejG  = eiG + 57344;
    // out-region: ping-pong bf16 halves; WeW3 staging aliases H1 (dead by mix0)
    u16* H0 = (u16*)d_out;
    u16* H1 = H0 + 44040192;
    u16* WeW3 = H1;
    float* attn0 = out + 44040192;
    float* attn1 = attn0 + 802816;
    float* attn2 = attn1 + 802816;

    // ---- prep ----
    conv_w<<<dim3(720), 256, 0, stream>>>(W_emb, gat_W, W_out, Wt);
    conv_x<<<dim3(4096), 256, 0, stream>>>((const float4*)features, H0, 11010048);
    conv_x<<<dim3(576), 256, 0, stream>>>((const float4*)W_emb, WeW3, 147456);
    conv_x<<<dim3(576), 256, 0, stream>>>((const float4*)(gat_W + 2 * 589824), WeW3 + 589824, 147456);
    prep_vecs<<<dim3(3), 256, 0, stream>>>(gat_W + 2 * 589824, gat_a + 2 * 1536, b_emb,
                                           Wt + 589824, w3ai, w3aj, bfus);
    // stacked prep GEMM: [We;W3] @ {W1t | W_out_t} -> scr (1536x768 fp32)
    gemm_bt<true, false><<<dim3(72), 256, 0, stream>>>(
        WeW3, Wt + 1 * 589824, Wt + 4 * 589824, nullptr, scr);
    conv_w2<<<dim3(288), 256, 0, stream>>>(scr, Wt + 5 * 589824);

    dim3 gg(2688);
    // layer 0 (embed fused): Wh1 = features_bf16 @ (We*W1) + be*W1
    gemm_bt<false, true><<<gg, 256, 0, stream>>>(
        H0, Wt + 5 * 589824, nullptr, bfus, Wh);
    gat_mix<true, false><<<dim3(4096), 256, 0, stream>>>(Wh, adj, gat_a, attn0, H1,
                                                         nullptr, nullptr, nullptr, nullptr);
    // layer 1: Wh2 = x1 @ W2 ; mix also emits ei3/ej3
    gemm_bt<false, true><<<gg, 256, 0, stream>>>(
        H1, Wt + 2 * 589824, nullptr, nullptr, Wh);
    gat_mix<true, true><<<dim3(4096), 256, 0, stream>>>(Wh, adj, gat_a + 1536, attn1, H0,
                                                        w3ai, w3aj, eiG, ejG);
    // layer 2 + out-proj fused: Z = x2 @ (W3*W_out); out = attn2 @ Z + b_out
    gemm_bt<false, true><<<gg, 256, 0, stream>>>(
        H0, Wt + 6 * 589824, nullptr, nullptr, Wh);
    gat_out<<<dim3(4096), 256, 0, stream>>>(Wh, adj, eiG, ejG, b_out, attn2, out);
}

// Round 14
// 593.839 us; speedup vs baseline: 1.2542x; 1.0754x over previous
//
#include <hip/hip_runtime.h>

typedef unsigned short u16;
typedef float f32x16 __attribute__((ext_vector_type(16)));
typedef short bf16x8 __attribute__((ext_vector_type(8)));
typedef unsigned short u16x8 __attribute__((ext_vector_type(8)));

#define ND 768
#define KD 768

__device__ __forceinline__ float bf2f(u16 u) {
    union { unsigned i; float f; } v; v.i = ((unsigned)u) << 16; return v.f;
}
__device__ __forceinline__ u16 f2bf(float f) {
    union { float f; unsigned u; } x; x.f = f;
    unsigned r = x.u + 0x7fffu + ((x.u >> 16) & 1u);
    return (u16)(r >> 16);
}
__device__ __forceinline__ void async16(const void* g, void* l) {
    __builtin_amdgcn_global_load_lds((const __attribute__((address_space(1))) void*)g,
                                     (__attribute__((address_space(3))) void*)l, 16, 0, 0);
}

// ---- fused prep: 3 weight transposes + We/W3 bf16 casts + features cast ----
// blocks 0..431: conv_w for m in {1,2,4} (W1, W2, W_out -> Wt K-major bf16)
// blocks 432..1583: row-major bf16 casts of We (576) and W3 (576)
// blocks 1584..5679: features fp32 -> bf16 (grid-stride, 4096 blocks)
__global__ __launch_bounds__(256) void mega_prep(const float* __restrict__ W_emb,
                                                 const float* __restrict__ gat_W,
                                                 const float* __restrict__ W_out,
                                                 const float4* __restrict__ features,
                                                 u16* __restrict__ Wt,
                                                 u16* __restrict__ WeBf,
                                                 u16* __restrict__ W3Bf,
                                                 u16* __restrict__ H0)
{
    __shared__ float lds[64][65];
    const int blk = blockIdx.x;
    const int tid = threadIdx.x;
    if (blk < 432) {
        const int mi = blk / 144;                 // 0,1,2
        const int mm = (mi == 0) ? 1 : (mi == 1) ? 2 : 4;
        const float* src = (mm == 4) ? W_out : gat_W + (size_t)(mm - 1) * 589824;
        const int r  = blk % 144;
        const int tr = r / 12, tc = r % 12;
        const int c  = tid & 63, w4 = tid >> 6;
        #pragma unroll
        for (int i = 0; i < 16; ++i) {
            int kk = i * 4 + w4;
            lds[kk][c] = src[(size_t)(tr * 64 + kk) * 768 + tc * 64 + c];
        }
        __syncthreads();
        u16* dst = Wt + (size_t)mm * 589824;
        #pragma unroll
        for (int i = 0; i < 16; ++i) {
            int nn = i * 4 + w4;
            dst[(size_t)(tc * 64 + nn) * 768 + tr * 64 + c] = f2bf(lds[c][nn]);
        }
    } else if (blk < 1584) {
        int bi = blk - 432;
        const float4* src;
        u16* dst;
        if (bi < 576) { src = (const float4*)W_emb; dst = WeBf; }
        else          { src = (const float4*)(gat_W + 2 * 589824); dst = W3Bf; bi -= 576; }
        const int i = bi * 256 + tid;             // < 147456
        float4 v = src[i];
        union { u16 s[4]; uint2 u; } o;
        o.s[0] = f2bf(v.x); o.s[1] = f2bf(v.y); o.s[2] = f2bf(v.z); o.s[3] = f2bf(v.w);
        ((uint2*)dst)[i] = o.u;
    } else {
        for (int i = (blk - 1584) * 256 + tid; i < 11010048; i += 4096 * 256) {
            float4 v = features[i];
            union { u16 s[4]; uint2 u; } o;
            o.s[0] = f2bf(v.x); o.s[1] = f2bf(v.y); o.s[2] = f2bf(v.z); o.s[3] = f2bf(v.w);
            ((uint2*)H0)[i] = o.u;
        }
    }
}

// ---- wave-parallel precompute: w3ai[d]=W3[d,:]·a_i, w3aj[d]=W3[d,:]·a_j,
//      bfus[d]=sum_j be[j]*bf16(W1[j][d]) (reads Wt1 row d, coalesced) ----
__global__ __launch_bounds__(256) void prep_vecs2(const float* __restrict__ W3,
                                                  const float* __restrict__ ga2,
                                                  const float* __restrict__ be,
                                                  const u16* __restrict__ Wt1,
                                                  float* __restrict__ w3ai,
                                                  float* __restrict__ w3aj,
                                                  float* __restrict__ bfus)
{
    const int lane = threadIdx.x & 63;
    const int d = blockIdx.x * 4 + (threadIdx.x >> 6);   // grid 192 -> d < 768
    const float* row = W3 + (size_t)d * 768;
    const u16* wrow = Wt1 + (size_t)d * 768;
    float ai = 0.f, aj = 0.f, bf = 0.f;
    for (int j = lane; j < 768; j += 64) {
        float w = row[j];
        ai += w * ga2[j];
        aj += w * ga2[768 + j];
        bf += be[j] * bf2f(wrow[j]);
    }
    #pragma unroll
    for (int off = 32; off; off >>= 1) {
        ai += __shfl_down(ai, off);
        aj += __shfl_down(aj, off);
        bf += __shfl_down(bf, off);
    }
    if (lane == 0) { w3ai[d] = ai; w3aj[d] = aj; bfus[d] = bf; }
}

// ---- bf16 GEMM: depth-2 prefetch, 3-buffer circular LDS, counted vmcnt(4) ----
// A2/Bt2: second operand pair selected when tm>=768 (stacked prep GEMM).
template<bool F32OUT, bool SWZ>
__global__ __launch_bounds__(256) void gemm_bt(const u16* __restrict__ A,
                                               const u16* __restrict__ A2,
                                               const u16* __restrict__ Bt,
                                               const u16* __restrict__ Bt2,
                                               const float* __restrict__ bias,
                                               void* __restrict__ Cout)
{
    __shared__ u16 lds3[3][2][4096];   // 48 KB: 3 slots x (A | B) x 128r x 32
    const int tid  = threadIdx.x;
    const int lane = tid & 63;
    const int wvb  = tid & ~63;
    const int wm   = ((tid >> 7) & 1) * 64;
    const int wn   = ((tid >> 6) & 1) * 64;
    const int wg = blockIdx.x;
    const int id = SWZ ? ((wg & 7) * 336 + (wg >> 3)) : wg;
    const int tn = (id % 6) * 128;
    const int tm = (id / 6) * 128;
    const bool hi = (A2 != nullptr) && (tm >= 768);
    const u16* AU  = hi ? A2 : A;
    const u16* BtU = hi ? Bt2 : Bt;
    const int tmA  = hi ? tm - 768 : tm;

    f32x16 acc[2][2] = {};

    const int r31 = lane & 31;
    const int l5  = lane >> 5;
    const int key = (r31 >> 1) & 3;

    const int row0 = tid >> 2;
    const int kc0  = (((tid & 3) ^ ((tid >> 3) & 3)) << 3);
    const u16* aSrc = AU  + (size_t)(tmA + row0) * KD + kc0;
    const u16* bSrc = BtU + (size_t)(tn + row0) * KD + kc0;

    #define STAGE(b, ks_) { const int k0 = (ks_) * 32;                       \
        async16(aSrc + k0,                   &lds3[b][0][wvb * 8]);          \
        async16(aSrc + (size_t)64 * KD + k0, &lds3[b][0][(256 + wvb) * 8]);  \
        async16(bSrc + k0,                   &lds3[b][1][wvb * 8]);          \
        async16(bSrc + (size_t)64 * KD + k0, &lds3[b][1][(256 + wvb) * 8]); }

    STAGE(0, 0);
    STAGE(1, 1);

    #pragma unroll 3
    for (int ks = 0; ks < KD / 32; ++ks) {
        const int cur = ks % 3;
        if (ks < KD / 32 - 1)
            asm volatile("s_waitcnt vmcnt(4)" ::: "memory");  // drain group ks only
        else
            asm volatile("s_waitcnt vmcnt(0)" ::: "memory");  // tail
        __builtin_amdgcn_s_barrier();
        asm volatile("" ::: "memory");
        if (ks + 2 < KD / 32) STAGE((ks + 2) % 3, ks + 2);    // depth-2 prefetch

        const u16* As = lds3[cur][0];
        const u16* Bs = lds3[cur][1];
        bf16x8 af[2][2], bf[2][2];
        #pragma unroll
        for (int fr = 0; fr < 2; ++fr)
            #pragma unroll
            for (int ka = 0; ka < 2; ++ka) {
                int chA = ((ka * 2 + l5) ^ key) << 3;
                af[fr][ka] = *(const bf16x8*)&As[(wm + fr * 32 + r31) * 32 + chA];
                bf[fr][ka] = *(const bf16x8*)&Bs[(wn + fr * 32 + r31) * 32 + chA];
            }
        #pragma unroll
        for (int fr = 0; fr < 2; ++fr)
            #pragma unroll
            for (int fc = 0; fc < 2; ++fc)
                #pragma unroll
                for (int ka = 0; ka < 2; ++ka)
                    acc[fr][fc] = __builtin_amdgcn_mfma_f32_32x32x16_bf16(
                        af[fr][ka], bf[fc][ka], acc[fr][fc], 0, 0, 0);
    }
    #undef STAGE

    // epilogue: 32x32 C/D layout col=lane&31, row=(reg&3)+8*(reg>>2)+4*(lane>>5)
    #pragma unroll
    for (int fc = 0; fc < 2; ++fc) {
        int col = tn + wn + fc * 32 + r31;
        float bv = bias ? bias[col] : 0.0f;
        #pragma unroll
        for (int fr = 0; fr < 2; ++fr) {
            int rowb = tm + wm + fr * 32 + 4 * l5;
            #pragma unroll
            for (int reg = 0; reg < 16; ++reg) {
                int row = rowb + (reg & 3) + 8 * (reg >> 2);
                float v = acc[fr][fc][reg] + bv;
                if (F32OUT)
                    ((float*)Cout)[(size_t)row * ND + col] = v;
                else
                    ((u16*)Cout)[(size_t)row * ND + col] = f2bf(v);
            }
        }
    }
}

// ---- fused GAT attention: ei/ej from staged Wh, softmax, mix, ELU ----
template<bool ELU, bool DOTS>
__global__ __launch_bounds__(256) void gat_mix(const u16* __restrict__ Wh,
                                               const float* __restrict__ adj,
                                               const float* __restrict__ avec,
                                               float* __restrict__ attn_out,
                                               u16* __restrict__ Xout,
                                               const float* __restrict__ w3ai,
                                               const float* __restrict__ w3aj,
                                               float* __restrict__ eiOut,
                                               float* __restrict__ ejOut)
{
    __shared__ u16 wh[14 * 768];
    __shared__ float s_ei[14], s_ej[14];
    __shared__ float s_attn[196];
    __shared__ float s_dots[14][2];
    const int b = blockIdx.x;
    const int tid = threadIdx.x;
    const u16* whb = Wh + (size_t)b * 10752;

    if (DOTS && tid < 28) ((float*)s_dots)[tid] = 0.f;
    for (int c = tid; c < 1344; c += 256)
        ((uint4*)wh)[c] = ((const uint4*)whb)[c];
    __syncthreads();

    if (tid < 224) {
        const int i = tid >> 4, l = tid & 15;
        float ai = 0.f, aj = 0.f;
        #pragma unroll
        for (int c = 0; c < 6; ++c) {
            int d = c * 128 + l * 8;
            u16x8 v  = *(const u16x8*)&wh[i * 768 + d];
            float4 x0 = *(const float4*)&avec[d];
            float4 x1 = *(const float4*)&avec[d + 4];
            float4 y0 = *(const float4*)&avec[768 + d];
            float4 y1 = *(const float4*)&avec[768 + d + 4];
            float w0 = bf2f(v[0]), w1 = bf2f(v[1]), w2 = bf2f(v[2]), w3 = bf2f(v[3]);
            float w4 = bf2f(v[4]), w5 = bf2f(v[5]), w6 = bf2f(v[6]), w7 = bf2f(v[7]);
            ai += w0*x0.x + w1*x0.y + w2*x0.z + w3*x0.w + w4*x1.x + w5*x1.y + w6*x1.z + w7*x1.w;
            aj += w0*y0.x + w1*y0.y + w2*y0.z + w3*y0.w + w4*y1.x + w5*y1.y + w6*y1.z + w7*y1.w;
        }
        #pragma unroll
        for (int off = 8; off; off >>= 1) {
            ai += __shfl_xor(ai, off);
            aj += __shfl_xor(aj, off);
        }
        if (l == 0) { s_ei[i] = ai; s_ej[i] = aj; }
    }
    __syncthreads();

    if (tid < 14) {
        const int i = tid;
        float e[14];
        float mx = -3.0e38f;
        #pragma unroll
        for (int j = 0; j < 14; ++j) {
            float ev = (adj[(size_t)b * 196 + i * 14 + j] > 0.f) ? (s_ei[i] + s_ej[j]) : -1.0e30f;
            e[j] = ev; mx = fmaxf(mx, ev);
        }
        float sum = 0.f;
        #pragma unroll
        for (int j = 0; j < 14; ++j) { float pp = __expf(e[j] - mx); e[j] = pp; sum += pp; }
        float inv = 1.0f / sum;
        #pragma unroll
        for (int j = 0; j < 14; ++j) s_attn[i * 14 + j] = e[j] * inv;
    }
    __syncthreads();

    if (tid < 196) attn_out[(size_t)b * 196 + tid] = s_attn[tid];

    for (int pp = tid; pp < 14 * 48; pp += 256) {
        const int i  = pp / 48;
        const int d0 = (pp % 48) * 16;
        float acc[16] = {};
        #pragma unroll
        for (int j = 0; j < 14; ++j) {
            float aw = s_attn[i * 14 + j];
            u16x8 wv0 = *(const u16x8*)&wh[j * 768 + d0];
            u16x8 wv1 = *(const u16x8*)&wh[j * 768 + d0 + 8];
            #pragma unroll
            for (int qq = 0; qq < 8; ++qq) {
                acc[qq]     += aw * bf2f(wv0[qq]);
                acc[8 + qq] += aw * bf2f(wv1[qq]);
            }
        }
        float pi = 0.f, pj = 0.f;
        union { u16 s[16]; uint4 u[2]; } o;
        #pragma unroll
        for (int qq = 0; qq < 16; ++qq) {
            float v = acc[qq];
            if (ELU && v < 0.f) v = __expf(v) - 1.0f;
            if (DOTS) { pi += v * w3ai[d0 + qq]; pj += v * w3aj[d0 + qq]; }
            o.s[qq] = f2bf(v);
        }
        if (DOTS) {
            atomicAdd(&s_dots[i][0], pi);
            atomicAdd(&s_dots[i][1], pj);
        }
        *(uint4*)&Xout[(size_t)b * 10752 + i * 768 + d0]     = o.u[0];
        *(uint4*)&Xout[(size_t)b * 10752 + i * 768 + d0 + 8] = o.u[1];
    }
    if (DOTS) {
        __syncthreads();
        if (tid < 14) {
            eiOut[(size_t)b * 14 + tid] = s_dots[tid][0];
            ejOut[(size_t)b * 14 + tid] = s_dots[tid][1];
        }
    }
}

// ---- final layer: softmax from precomputed ei3/ej3, out = attn2 @ Z + b_out ----
__global__ __launch_bounds__(256) void gat_out(const u16* __restrict__ Z,
                                               const float* __restrict__ adj,
                                               const float* __restrict__ eiG,
                                               const float* __restrict__ ejG,
                                               const float* __restrict__ b_out,
                                               float* __restrict__ attn_out,
                                               float* __restrict__ outp)
{
    __shared__ u16 wh[14 * 768];
    __shared__ float s_attn[196];
    const int b = blockIdx.x;
    const int tid = threadIdx.x;
    const u16* zb = Z + (size_t)b * 10752;

    for (int c = tid; c < 1344; c += 256)
        ((uint4*)wh)[c] = ((const uint4*)zb)[c];

    if (tid < 14) {
        const int i = tid;
        float ei = eiG[(size_t)b * 14 + i];
        float e[14];
        float mx = -3.0e38f;
        #pragma unroll
        for (int j = 0; j < 14; ++j) {
            float ev = (adj[(size_t)b * 196 + i * 14 + j] > 0.f)
                           ? (ei + ejG[(size_t)b * 14 + j]) : -1.0e30f;
            e[j] = ev; mx = fmaxf(mx, ev);
        }
        float sum = 0.f;
        #pragma unroll
        for (int j = 0; j < 14; ++j) { float pp = __expf(e[j] - mx); e[j] = pp; sum += pp; }
        float inv = 1.0f / sum;
        #pragma unroll
        for (int j = 0; j < 14; ++j) s_attn[i * 14 + j] = e[j] * inv;
    }
    __syncthreads();

    if (tid < 196) attn_out[(size_t)b * 196 + tid] = s_attn[tid];

    for (int pp = tid; pp < 14 * 48; pp += 256) {
        const int i  = pp / 48;
        const int d0 = (pp % 48) * 16;
        float acc[16];
        #pragma unroll
        for (int qq = 0; qq < 16; ++qq) acc[qq] = b_out[d0 + qq];
        #pragma unroll
        for (int j = 0; j < 14; ++j) {
            float aw = s_attn[i * 14 + j];
            u16x8 wv0 = *(const u16x8*)&wh[j * 768 + d0];
            u16x8 wv1 = *(const u16x8*)&wh[j * 768 + d0 + 8];
            #pragma unroll
            for (int qq = 0; qq < 8; ++qq) {
                acc[qq]     += aw * bf2f(wv0[qq]);
                acc[8 + qq] += aw * bf2f(wv1[qq]);
            }
        }
        float* dst = &outp[(size_t)b * 10752 + i * 768 + d0];
        *(float4*)(dst)      = *(float4*)&acc[0];
        *(float4*)(dst + 4)  = *(float4*)&acc[4];
        *(float4*)(dst + 8)  = *(float4*)&acc[8];
        *(float4*)(dst + 12) = *(float4*)&acc[12];
    }
}

extern "C" void kernel_launch(void* const* d_in, const int* in_sizes, int n_in,
                              void* d_out, int out_size, void* d_ws, size_t ws_size,
                              hipStream_t stream)
{
    const float* features = (const float*)d_in[0];
    const float* adj      = (const float*)d_in[1];
    const float* W_emb    = (const float*)d_in[2];
    const float* b_emb    = (const float*)d_in[3];
    const float* gat_W    = (const float*)d_in[4];
    const float* gat_a    = (const float*)d_in[5];
    const float* W_out    = (const float*)d_in[6];
    const float* b_out    = (const float*)d_in[7];
    float* out = (float*)d_out;

    // ws: Wh (bf16 57344x768) | Wt[7] | w3ai | w3aj | bfus | eiG | ejG
    u16* Wh = (u16*)d_ws;
    u16* Wt = Wh + 44040192;
    float* w3ai = (float*)(Wt + 7 * 589824);
    float* w3aj = w3ai + 768;
    float* bfus = w3aj + 768;
    float* eiG  = bfus + 768;
    float* ejG  = eiG + 57344;
    // out-region: ping-pong bf16 halves; WeW3 staging aliases H1 (dead by mix0)
    u16* H0 = (u16*)d_out;
    u16* H1 = H0 + 44040192;
    u16* WeBf = H1;
    u16* W3Bf = H1 + 589824;
    float* attn0 = out + 44040192;
    float* attn1 = attn0 + 802816;
    float* attn2 = attn1 + 802816;

    // ---- prep (3 launches) ----
    mega_prep<<<dim3(5680), 256, 0, stream>>>(W_emb, gat_W, W_out,
                                              (const float4*)features,
                                              Wt, WeBf, W3Bf, H0);
    prep_vecs2<<<dim3(192), 256, 0, stream>>>(gat_W + 2 * 589824, gat_a + 2 * 1536, b_emb,
                                              Wt + 589824, w3ai, w3aj, bfus);
    // stacked prep GEMM writes fused weights DIRECTLY as bf16 K-major:
    // rows 0-767:  C'[n][k] = sum_j Wt1[n][j]*WeBf[k][j] = (We*W1)[k][n] -> Wt5
    // rows 768+ :  C'[n][k] = sum_j Wt4[n][j]*W3Bf[k][j] = (W3*Wout)[k][n] -> Wt6
    gemm_bt<false, false><<<dim3(72), 256, 0, stream>>>(
        Wt + 1 * 589824, Wt + 4 * 589824, WeBf, W3Bf, nullptr, Wt + 5 * 589824);

    dim3 gg(2688);
    // layer 0 (embed fused): Wh1 = features_bf16 @ (We*W1) + be*W1
    gemm_bt<false, true><<<gg, 256, 0, stream>>>(
        H0, nullptr, Wt + 5 * 589824, nullptr, bfus, Wh);
    gat_mix<true, false><<<dim3(4096), 256, 0, stream>>>(Wh, adj, gat_a, attn0, H1,
                                                         nullptr, nullptr, nullptr, nullptr);
    // layer 1: Wh2 = x1 @ W2 ; mix also emits ei3/ej3
    gemm_bt<false, true><<<gg, 256, 0, stream>>>(
        H1, nullptr, Wt + 2 * 589824, nullptr, nullptr, Wh);
    gat_mix<true, true><<<dim3(4096), 256, 0, stream>>>(Wh, adj, gat_a + 1536, attn1, H0,
                                                        w3ai, w3aj, eiG, ejG);
    // layer 2 + out-proj fused: Z = x2 @ (W3*W_out); out = attn2 @ Z + b_out
    gemm_bt<false, true><<<gg, 256, 0, stream>>>(
        H0, nullptr, Wt + 6 * 589824, nullptr, nullptr, Wh);
    gat_out<<<dim3(4096), 256, 0, stream>>>(Wh, adj, eiG, ejG, b_out, attn2, out);
}